// Round 1
// baseline (1229.287 us; speedup 1.0000x reference)
//
#include <hip/hip_runtime.h>
#include <stdint.h>

#define N_ 4096
#define D_ 512
#define H_ 8
#define E_ 131072
#define TD_ 1536
#define FD_ 2048

typedef unsigned short u16;
typedef __bf16 bf16x8 __attribute__((ext_vector_type(8)));
typedef u16 u16x8 __attribute__((ext_vector_type(8)));
typedef float f32x4 __attribute__((ext_vector_type(4)));

__device__ __forceinline__ u16 f2bf(float f) {
  union { float f; uint32_t u; } v; v.f = f;
  return (u16)((v.u + 0x7FFFu + ((v.u >> 16) & 1u)) >> 16);
}
__device__ __forceinline__ float bf2f(u16 b) {
  union { uint32_t u; float f; } v; v.u = ((uint32_t)b) << 16; return v.f;
}

// ---------------- GEMM: C[M,N] = A[M,K] @ B[N,K]^T (+bias) -----------------
// MODE: 0 = f32 store, 1 = bf16 store (scale applied), 2 = f32 atomicAdd,
//       3 = exact-GELU then bf16 store
template <int BM, int BN, int BK, int WM, int WN, int FM, int FN, int MODE, bool BIAS>
__global__ __launch_bounds__(WM * WN * 64) void gemm_bt(
    const u16* __restrict__ A, int lda, const u16* __restrict__ B, int ldb,
    void* __restrict__ Cout, int ldc, const float* __restrict__ bias,
    float scale, int Kchunk)
{
  static_assert(BM == WM * FM * 16 && BN == WN * FN * 16, "tile shape");
  __shared__ alignas(16) u16 As[BM * BK];
  __shared__ alignas(16) u16 Bs[BN * BK];
  constexpr int NT = WM * WN * 64;
  const int tid = threadIdx.x;
  const int lane = tid & 63;
  const int wave = tid >> 6;
  const long tm = (long)blockIdx.x * BM;
  const long tn = (long)blockIdx.y * BN;
  const long k0 = (long)blockIdx.z * Kchunk;
  const int wm0 = (wave / WN) * (FM * 16);
  const int wn0 = (wave % WN) * (FN * 16);

  f32x4 acc[FM][FN] = {};

  constexpr int A_LOADS = (BM * BK) / (NT * 8);
  constexpr int B_LOADS = (BN * BK) / (NT * 8);

  for (int kt = 0; kt < Kchunk; kt += BK) {
    const long kb = k0 + kt;
#pragma unroll
    for (int i = 0; i < A_LOADS; ++i) {
      int s = (i * NT + tid) * 8;
      int row = s / BK, kk = s % BK;
      *(u16x8*)(&As[row * BK + kk]) =
          *(const u16x8*)(A + (tm + row) * (long)lda + kb + kk);
    }
#pragma unroll
    for (int i = 0; i < B_LOADS; ++i) {
      int s = (i * NT + tid) * 8;
      int row = s / BK, kk = s % BK;
      *(u16x8*)(&Bs[row * BK + kk]) =
          *(const u16x8*)(B + (tn + row) * (long)ldb + kb + kk);
    }
    __syncthreads();
#pragma unroll
    for (int kk = 0; kk < BK; kk += 32) {
      bf16x8 af[FM], bfr[FN];
#pragma unroll
      for (int i = 0; i < FM; ++i)
        af[i] = *(const bf16x8*)(&As[(wm0 + i * 16 + (lane & 15)) * BK + kk + (lane >> 4) * 8]);
#pragma unroll
      for (int j = 0; j < FN; ++j)
        bfr[j] = *(const bf16x8*)(&Bs[(wn0 + j * 16 + (lane & 15)) * BK + kk + (lane >> 4) * 8]);
#pragma unroll
      for (int i = 0; i < FM; ++i)
#pragma unroll
        for (int j = 0; j < FN; ++j)
          acc[i][j] = __builtin_amdgcn_mfma_f32_16x16x32_bf16(af[i], bfr[j], acc[i][j], 0, 0, 0);
    }
    __syncthreads();
  }

#pragma unroll
  for (int i = 0; i < FM; ++i) {
#pragma unroll
    for (int j = 0; j < FN; ++j) {
      const long col = tn + wn0 + j * 16 + (lane & 15);
      const float bv = BIAS ? bias[col] : 0.0f;
#pragma unroll
      for (int r = 0; r < 4; ++r) {
        const long row = tm + wm0 + i * 16 + (lane >> 4) * 4 + r;
        float v = acc[i][j][r] * scale + bv;
        if constexpr (MODE == 0) {
          ((float*)Cout)[row * (long)ldc + col] = v;
        } else if constexpr (MODE == 1) {
          ((u16*)Cout)[row * (long)ldc + col] = f2bf(v);
        } else if constexpr (MODE == 2) {
          atomicAdd(&((float*)Cout)[row * (long)ldc + col], v);
        } else {
          float ge = 0.5f * v * (1.0f + erff(v * 0.70710678118654752f));
          ((u16*)Cout)[row * (long)ldc + col] = f2bf(ge);
        }
      }
    }
  }
}

// ---------------- elementwise / reduction kernels ----------------

__global__ void conv_bf16(const float* __restrict__ src, int sld, int C,
                          u16* __restrict__ dst, int total) {
  int i = blockIdx.x * 256 + threadIdx.x;
  if (i >= total) return;
  if (sld == C) { dst[i] = f2bf(src[i]); return; }
  int r = i / C, c = i - r * C;
  dst[i] = f2bf(src[(size_t)r * sld + c]);
}

__global__ __launch_bounds__(1024) void transpose_bf16(const u16* __restrict__ src, int sld,
                                                       u16* __restrict__ dst, int dld) {
  __shared__ u16 tile[32][33];
  int r = blockIdx.y * 32 + threadIdx.y;
  int c = blockIdx.x * 32 + threadIdx.x;
  tile[threadIdx.y][threadIdx.x] = src[(size_t)r * sld + c];
  __syncthreads();
  int rr = blockIdx.x * 32 + threadIdx.y;
  int cc = blockIdx.y * 32 + threadIdx.x;
  dst[(size_t)rr * dld + cc] = tile[threadIdx.x][threadIdx.y];
}

__global__ void edge_kernel(const int* __restrict__ ei, float* __restrict__ S,
                            float* __restrict__ deg) {
  int e = blockIdx.x * 256 + threadIdx.x;
  int s = ei[e], d = ei[E_ + e];
  atomicAdd(&S[(size_t)d * N_ + s], 1.0f);
  atomicAdd(&deg[d], 1.0f);
}

__global__ __launch_bounds__(128) void ln12_kernel(const float* __restrict__ x,
    const float* __restrict__ g1, const float* __restrict__ b1,
    const float* __restrict__ g2, const float* __restrict__ b2,
    float* __restrict__ xn1, u16* __restrict__ xn1b, u16* __restrict__ xn2b)
{
  int row = blockIdx.x, t = threadIdx.x;
  size_t base = (size_t)row * D_ + t * 4;
  f32x4 v = *(const f32x4*)(x + base);
  float s = v[0] + v[1] + v[2] + v[3];
  float ss = v[0]*v[0] + v[1]*v[1] + v[2]*v[2] + v[3]*v[3];
  __shared__ float red[4];
  for (int off = 32; off; off >>= 1) { s += __shfl_down(s, off); ss += __shfl_down(ss, off); }
  if ((t & 63) == 0) { red[t >> 6] = s; red[2 + (t >> 6)] = ss; }
  __syncthreads();
  s = red[0] + red[1]; ss = red[2] + red[3];
  float mu = s * (1.0f / D_);
  float inv = rsqrtf(ss * (1.0f / D_) - mu * mu + 1e-5f);
#pragma unroll
  for (int i = 0; i < 4; ++i) {
    int c = t * 4 + i;
    float xh = (v[i] - mu) * inv;
    float o1 = xh * g1[c] + b1[c];
    float o2 = xh * g2[c] + b2[c];
    xn1[base + i] = o1;
    xn1b[base + i] = f2bf(o1);
    xn2b[base + i] = f2bf(o2);
  }
}

__global__ void finalize_aggr(const float* __restrict__ aggp, const float* __restrict__ part2,
                              const float* __restrict__ deg, const float* __restrict__ msg_b,
                              u16* __restrict__ aggrb) {
  int i = blockIdx.x * 256 + threadIdx.x;
  int n = i >> 9, d = i & 511;
  float dg = deg[n];
  float v = (aggp[i] + dg * (part2[i] + msg_b[d])) / fmaxf(dg, 1.0f);
  aggrb[i] = f2bf(v);
}

__global__ void gru_kernel(const float* __restrict__ gi, const float* __restrict__ gh,
                           const float* __restrict__ xn1, float* __restrict__ xm) {
  int i = blockIdx.x * 256 + threadIdx.x;
  int n = i >> 9, d = i & 511;
  size_t b = (size_t)n * TD_ + d;
  float ir = gi[b], iz = gi[b + 512], in_ = gi[b + 1024];
  float hr = gh[b], hz = gh[b + 512], hn = gh[b + 1024];
  float r = 1.0f / (1.0f + expf(-(ir + hr)));
  float z = 1.0f / (1.0f + expf(-(iz + hz)));
  float nn = tanhf(in_ + r * hn);
  xm[i] = (1.0f - z) * nn + z * xn1[i];
}

template <bool FIRST>
__global__ __launch_bounds__(256) void softmax_kernel(u16* __restrict__ w,
                                                      float* __restrict__ attn) {
  int row = blockIdx.x, t = threadIdx.x;
  u16* wr = w + (size_t)row * N_;
  float p[16];
  u16x8 v0 = *(const u16x8*)(wr + t * 16);
  u16x8 v1 = *(const u16x8*)(wr + t * 16 + 8);
#pragma unroll
  for (int i = 0; i < 8; ++i) { p[i] = bf2f(v0[i]); p[8 + i] = bf2f(v1[i]); }
  float mx = p[0];
#pragma unroll
  for (int i = 1; i < 16; ++i) mx = fmaxf(mx, p[i]);
  __shared__ float red[4];
  for (int off = 32; off; off >>= 1) mx = fmaxf(mx, __shfl_down(mx, off));
  if ((t & 63) == 0) red[t >> 6] = mx;
  __syncthreads();
  mx = fmaxf(fmaxf(red[0], red[1]), fmaxf(red[2], red[3]));
  __syncthreads();
  float sum = 0.0f;
#pragma unroll
  for (int i = 0; i < 16; ++i) { p[i] = expf(p[i] - mx); sum += p[i]; }
  for (int off = 32; off; off >>= 1) sum += __shfl_down(sum, off);
  if ((t & 63) == 0) red[t >> 6] = sum;
  __syncthreads();
  float inv = 1.0f / (red[0] + red[1] + red[2] + red[3]);
  float* ar = attn + (size_t)row * N_ + t * 16;
#pragma unroll
  for (int i = 0; i < 16; ++i) {
    float wv = p[i] * inv;
    wr[t * 16 + i] = f2bf(wv);
    if (FIRST) ar[i] = 0.125f * wv; else ar[i] += 0.125f * wv;
  }
}

__global__ __launch_bounds__(64) void gate_kernel(const float* __restrict__ xm,
    const float* __restrict__ xa, const float* __restrict__ gw,
    const float* __restrict__ gb, float* __restrict__ g) {
  int n = blockIdx.x, l = threadIdx.x;
  const float* m = xm + (size_t)n * D_;
  const float* a = xa + (size_t)n * D_;
  float s = 0.0f;
  for (int j = l; j < D_; j += 64) s += m[j] * gw[j] + a[j] * gw[D_ + j];
  for (int off = 32; off; off >>= 1) s += __shfl_down(s, off);
  if (l == 0) g[n] = 1.0f / (1.0f + expf(-(s + gb[0])));
}

__global__ __launch_bounds__(128) void combine_ln3(const float* __restrict__ x,
    const float* __restrict__ xm, const float* __restrict__ xa, const float* __restrict__ g,
    const float* __restrict__ g3, const float* __restrict__ b3,
    float* __restrict__ xc, u16* __restrict__ xn3b)
{
  int row = blockIdx.x, t = threadIdx.x;
  size_t base = (size_t)row * D_ + t * 4;
  float gg = g[row];
  f32x4 xv = *(const f32x4*)(x + base);
  f32x4 mv = *(const f32x4*)(xm + base);
  f32x4 av = *(const f32x4*)(xa + base);
  f32x4 cv = xv + gg * mv + (1.0f - gg) * av;
  *(f32x4*)(xc + base) = cv;
  float s = cv[0] + cv[1] + cv[2] + cv[3];
  float ss = cv[0]*cv[0] + cv[1]*cv[1] + cv[2]*cv[2] + cv[3]*cv[3];
  __shared__ float red[4];
  for (int off = 32; off; off >>= 1) { s += __shfl_down(s, off); ss += __shfl_down(ss, off); }
  if ((t & 63) == 0) { red[t >> 6] = s; red[2 + (t >> 6)] = ss; }
  __syncthreads();
  s = red[0] + red[1]; ss = red[2] + red[3];
  float mu = s * (1.0f / D_);
  float inv = rsqrtf(ss * (1.0f / D_) - mu * mu + 1e-5f);
#pragma unroll
  for (int i = 0; i < 4; ++i) {
    int c = t * 4 + i;
    float xh = (cv[i] - mu) * inv;
    xn3b[base + i] = f2bf(xh * g3[c] + b3[c]);
  }
}

__global__ void final_add(const float* __restrict__ a, const float* __restrict__ b,
                          float* __restrict__ o) {
  size_t i = ((size_t)blockIdx.x * 256 + threadIdx.x) * 4;
  f32x4 va = *(const f32x4*)(a + i);
  f32x4 vb = *(const f32x4*)(b + i);
  *(f32x4*)(o + i) = va + vb;
}

// ------------------------------ launch ------------------------------

extern "C" void kernel_launch(void* const* d_in, const int* in_sizes, int n_in,
                              void* d_out, int out_size, void* d_ws, size_t ws_size,
                              hipStream_t stream)
{
  (void)in_sizes; (void)n_in; (void)out_size;
  const float* x         = (const float*)d_in[0];
  const int*   ei        = (const int*)d_in[1];
  const float* ln1_g     = (const float*)d_in[2];
  const float* ln1_b     = (const float*)d_in[3];
  const float* ln2_g     = (const float*)d_in[4];
  const float* ln2_b     = (const float*)d_in[5];
  const float* ln3_g     = (const float*)d_in[6];
  const float* ln3_b     = (const float*)d_in[7];
  const float* in_proj_w = (const float*)d_in[8];
  const float* in_proj_b = (const float*)d_in[9];
  const float* out_proj_w= (const float*)d_in[10];
  const float* out_proj_b= (const float*)d_in[11];
  const float* msg_w     = (const float*)d_in[12];
  const float* msg_b     = (const float*)d_in[13];
  const float* gru_wih   = (const float*)d_in[14];
  const float* gru_whh   = (const float*)d_in[15];
  const float* gru_bih   = (const float*)d_in[16];
  const float* gru_bhh   = (const float*)d_in[17];
  const float* ffn_w1    = (const float*)d_in[18];
  const float* ffn_b1    = (const float*)d_in[19];
  const float* ffn_w2    = (const float*)d_in[20];
  const float* ffn_b2    = (const float*)d_in[21];
  const float* gate_w    = (const float*)d_in[22];
  const float* gate_b    = (const float*)d_in[23];

  char* ws = (char*)d_ws;
  size_t o = 0;
  auto alloc = [&](size_t b) { size_t r = o; o += (b + 255) & ~(size_t)255; return r; };
  const size_t o_xn1   = alloc((size_t)N_ * D_ * 4);
  const size_t o_xn1b  = alloc((size_t)N_ * D_ * 2);
  const size_t o_xn2b  = alloc((size_t)N_ * D_ * 2);
  const size_t o_xn1T  = alloc((size_t)N_ * D_ * 2);
  const size_t o_ipb   = alloc((size_t)TD_ * D_ * 2);
  const size_t o_w1b   = alloc((size_t)D_ * D_ * 2);
  const size_t o_w2b   = alloc((size_t)D_ * D_ * 2);
  const size_t o_wihb  = alloc((size_t)TD_ * D_ * 2);
  const size_t o_whhb  = alloc((size_t)TD_ * D_ * 2);
  const size_t o_opb   = alloc((size_t)D_ * D_ * 2);
  const size_t o_f1b   = alloc((size_t)FD_ * D_ * 2);
  const size_t o_f2b   = alloc((size_t)D_ * FD_ * 2);
  const size_t o_deg   = alloc((size_t)N_ * 4);
  const size_t o_gv    = alloc((size_t)N_ * 4);
  const size_t o_part2 = alloc((size_t)N_ * D_ * 4);
  const size_t o_aggp  = alloc((size_t)N_ * D_ * 4);
  const size_t o_aggrb = alloc((size_t)N_ * D_ * 2);
  const size_t o_gsb   = alloc((size_t)N_ * D_ * 2);
  const size_t o_xm    = alloc((size_t)N_ * D_ * 4);
  const size_t o_xn3b  = alloc((size_t)N_ * D_ * 2);
  const size_t o_ctxb  = alloc((size_t)N_ * D_ * 2);
  const size_t o_big1  = alloc((size_t)N_ * N_ * 4);  // S f32 -> w bf16
  const size_t o_big2  = alloc((size_t)N_ * N_ * 2);  // Sb    -> h1b
  const size_t o_rn    = alloc((size_t)N_ * TD_ * 4); // gi -> qkvb+vT+ctx
  const size_t o_ro    = alloc((size_t)N_ * TD_ * 4); // gh -> x_attn+xc+ffn2o
  if (ws_size < o) return;

  float* xn1  = (float*)(ws + o_xn1);
  u16* xn1b   = (u16*)(ws + o_xn1b);
  u16* xn2b   = (u16*)(ws + o_xn2b);
  u16* xn1T   = (u16*)(ws + o_xn1T);
  u16* ipb    = (u16*)(ws + o_ipb);
  u16* w1b    = (u16*)(ws + o_w1b);
  u16* w2b    = (u16*)(ws + o_w2b);
  u16* wihb   = (u16*)(ws + o_wihb);
  u16* whhb   = (u16*)(ws + o_whhb);
  u16* opb    = (u16*)(ws + o_opb);
  u16* f1b    = (u16*)(ws + o_f1b);
  u16* f2b    = (u16*)(ws + o_f2b);
  float* deg  = (float*)(ws + o_deg);
  float* gv   = (float*)(ws + o_gv);
  float* part2= (float*)(ws + o_part2);
  float* aggp = (float*)(ws + o_aggp);
  u16* aggrb  = (u16*)(ws + o_aggrb);
  u16* gsb    = (u16*)(ws + o_gsb);
  float* xm   = (float*)(ws + o_xm);
  u16* xn3b   = (u16*)(ws + o_xn3b);
  u16* ctxb   = (u16*)(ws + o_ctxb);
  float* Sf   = (float*)(ws + o_big1);
  u16* wbuf   = (u16*)(ws + o_big1);
  u16* Sb     = (u16*)(ws + o_big2);
  u16* h1b    = (u16*)(ws + o_big2);
  float* gi   = (float*)(ws + o_rn);
  u16* qkvb   = (u16*)(ws + o_rn);
  u16* vT     = (u16*)(ws + o_rn + (size_t)N_ * TD_ * 2);
  float* ctx  = (float*)(ws + o_rn + (size_t)N_ * TD_ * 2 + (size_t)D_ * N_ * 2);
  float* gh   = (float*)(ws + o_ro);
  float* xattn= (float*)(ws + o_ro);
  float* xc   = (float*)(ws + o_ro + (size_t)N_ * D_ * 4);
  float* ffn2o= (float*)(ws + o_ro + (size_t)N_ * D_ * 8);

  float* outp = (float*)d_out;
  float* attn = (float*)d_out + (size_t)N_ * D_;

  hipMemsetAsync(Sf, 0, (size_t)N_ * N_ * 4, stream);
  hipMemsetAsync(deg, 0, (size_t)N_ * 4, stream);

  // weight conversions to bf16
  conv_bf16<<<3072, 256, 0, stream>>>(in_proj_w, 512, 512, ipb, TD_ * D_);
  conv_bf16<<<3072, 256, 0, stream>>>(gru_wih, 512, 512, wihb, TD_ * D_);
  conv_bf16<<<3072, 256, 0, stream>>>(gru_whh, 512, 512, whhb, TD_ * D_);
  conv_bf16<<<1024, 256, 0, stream>>>(out_proj_w, 512, 512, opb, D_ * D_);
  conv_bf16<<<4096, 256, 0, stream>>>(ffn_w1, 512, 512, f1b, FD_ * D_);
  conv_bf16<<<4096, 256, 0, stream>>>(ffn_w2, 2048, 2048, f2b, D_ * FD_);
  conv_bf16<<<1024, 256, 0, stream>>>(msg_w, 1024, 512, w1b, D_ * D_);
  conv_bf16<<<1024, 256, 0, stream>>>(msg_w + 512, 1024, 512, w2b, D_ * D_);

  // LN1/LN2 (shared mean/var)
  ln12_kernel<<<N_, 128, 0, stream>>>(x, ln1_g, ln1_b, ln2_g, ln2_b, xn1, xn1b, xn2b);
  transpose_bf16<<<dim3(16, 128), dim3(32, 32), 0, stream>>>(xn1b, D_, xn1T, N_);

  // adjacency-count matrix + degree
  edge_kernel<<<512, 256, 0, stream>>>(ei, Sf, deg);
  conv_bf16<<<65536, 256, 0, stream>>>(Sf, N_, N_, Sb, N_ * N_);

  // gather_sum = S @ xn1   (as S @ xn1T^T)
  gemm_bt<128, 64, 64, 4, 1, 2, 4, 1, false><<<dim3(32, 8), 256, 0, stream>>>(
      Sb, N_, xn1T, N_, gsb, D_, nullptr, 1.0f, N_);
  // part2 = xn1 @ W2^T
  gemm_bt<128, 64, 64, 4, 1, 2, 4, 0, false><<<dim3(32, 8), 256, 0, stream>>>(
      xn1b, D_, w2b, D_, part2, D_, nullptr, 1.0f, D_);
  // aggr_pre = gather_sum @ W1^T
  gemm_bt<128, 64, 64, 4, 1, 2, 4, 0, false><<<dim3(32, 8), 256, 0, stream>>>(
      gsb, D_, w1b, D_, aggp, D_, nullptr, 1.0f, D_);
  finalize_aggr<<<8192, 256, 0, stream>>>(aggp, part2, deg, msg_b, aggrb);

  // GRU gates
  gemm_bt<128, 128, 64, 2, 2, 4, 4, 0, true><<<dim3(32, 12), 256, 0, stream>>>(
      aggrb, D_, wihb, D_, gi, TD_, gru_bih, 1.0f, D_);
  gemm_bt<128, 128, 64, 2, 2, 4, 4, 0, true><<<dim3(32, 12), 256, 0, stream>>>(
      xn1b, D_, whhb, D_, gh, TD_, gru_bhh, 1.0f, D_);
  gru_kernel<<<8192, 256, 0, stream>>>(gi, gh, xn1, xm);

  // attention: qkv projection (bf16 out, gi region now dead)
  gemm_bt<128, 128, 64, 2, 2, 4, 4, 1, true><<<dim3(32, 12), 256, 0, stream>>>(
      xn2b, D_, ipb, D_, qkvb, TD_, in_proj_b, 1.0f, D_);
  transpose_bf16<<<dim3(16, 128), dim3(32, 32), 0, stream>>>(qkvb + 1024, TD_, vT, N_);
  hipMemsetAsync(ctx, 0, (size_t)N_ * D_ * 4, stream);

  for (int h = 0; h < H_; ++h) {
    gemm_bt<128, 128, 64, 2, 2, 4, 4, 1, false><<<dim3(32, 32), 256, 0, stream>>>(
        qkvb + h * 64, TD_, qkvb + 512 + h * 64, TD_, wbuf, N_, nullptr, 0.125f, 64);
    if (h == 0)
      softmax_kernel<true><<<N_, 256, 0, stream>>>(wbuf, attn);
    else
      softmax_kernel<false><<<N_, 256, 0, stream>>>(wbuf, attn);
    gemm_bt<128, 64, 64, 4, 1, 2, 4, 2, false><<<dim3(32, 1, 8), 256, 0, stream>>>(
        wbuf, N_, vT + (size_t)h * 64 * N_, N_, ctx + h * 64, D_, nullptr, 1.0f, 512);
  }

  conv_bf16<<<8192, 256, 0, stream>>>(ctx, 512, 512, ctxb, N_ * D_);
  gemm_bt<128, 64, 64, 4, 1, 2, 4, 0, true><<<dim3(32, 8), 256, 0, stream>>>(
      ctxb, D_, opb, D_, xattn, D_, out_proj_b, 1.0f, D_);

  // gated combine + LN3
  gate_kernel<<<N_, 64, 0, stream>>>(xm, xattn, gate_w, gate_b, gv);
  combine_ln3<<<N_, 128, 0, stream>>>(x, xm, xattn, gv, ln3_g, ln3_b, xc, xn3b);

  // FFN (GELU fused into GEMM epilogue)
  gemm_bt<128, 128, 64, 2, 2, 4, 4, 3, true><<<dim3(32, 16), 256, 0, stream>>>(
      xn3b, D_, f1b, D_, h1b, FD_, ffn_b1, 1.0f, D_);
  gemm_bt<128, 64, 64, 4, 1, 2, 4, 0, true><<<dim3(32, 8), 256, 0, stream>>>(
      h1b, FD_, f2b, FD_, ffn2o, D_, ffn_b2, 1.0f, FD_);
  final_add<<<2048, 256, 0, stream>>>(xc, ffn2o, outp);
}

// Round 3
// 768.465 us; speedup vs baseline: 1.5997x; 1.5997x over previous
//
#include <hip/hip_runtime.h>
#include <stdint.h>

#define N_ 4096
#define D_ 512
#define H_ 8
#define E_ 131072
#define TD_ 1536
#define FD_ 2048
#define CM_ 1024  // attention row-chunk

typedef unsigned short u16;
typedef __bf16 bf16x8 __attribute__((ext_vector_type(8)));
typedef u16 u16x8 __attribute__((ext_vector_type(8)));
typedef float f32x4 __attribute__((ext_vector_type(4)));

__device__ __forceinline__ u16 f2bf(float f) {
  union { float f; uint32_t u; } v; v.f = f;
  return (u16)((v.u + 0x7FFFu + ((v.u >> 16) & 1u)) >> 16);
}
__device__ __forceinline__ float bf2f(u16 b) {
  union { uint32_t u; float f; } v; v.u = ((uint32_t)b) << 16; return v.f;
}

// ---------------- GEMM: C[M,N] = A[M,K] @ B[N,K]^T (+bias) -----------------
// MODE: 0 = f32 store, 1 = bf16 store (scale applied), 2 = f32 atomicAdd,
//       3 = exact-GELU then bf16 store
// HM (head mode): 0 = none (y = N-block, z = split-K)
//                 1 = z is head index (A/B/C shifted by hA/hB/hC, no split-K)
//                 2 = y is head index (N-block forced 0), z = split-K
template <int BM, int BN, int BK, int WM, int WN, int FM, int FN, int MODE, bool BIAS, int HM>
__global__ __launch_bounds__(WM * WN * 64) void gemm_bt(
    const u16* __restrict__ A, int lda, const u16* __restrict__ B, int ldb,
    void* __restrict__ Cout, int ldc, const float* __restrict__ bias,
    float scale, int Kchunk, size_t hA, size_t hB, size_t hC)
{
  static_assert(BM == WM * FM * 16 && BN == WN * FN * 16, "tile shape");
  static_assert(BK == 64, "LDS swizzle assumes BK=64");
  __shared__ alignas(16) u16 As[BM * BK];
  __shared__ alignas(16) u16 Bs[BN * BK];
  constexpr int NT = WM * WN * 64;
  const int tid = threadIdx.x;
  const int lane = tid & 63;
  const int wave = tid >> 6;
  const long tm = (long)blockIdx.x * BM;
  long tn, k0;
  size_t cOff = 0;
  if constexpr (HM == 1) {
    A += (size_t)blockIdx.z * hA; B += (size_t)blockIdx.z * hB; cOff = (size_t)blockIdx.z * hC;
    tn = (long)blockIdx.y * BN; k0 = 0;
  } else if constexpr (HM == 2) {
    A += (size_t)blockIdx.y * hA; B += (size_t)blockIdx.y * hB; cOff = (size_t)blockIdx.y * hC;
    tn = 0; k0 = (long)blockIdx.z * Kchunk;
  } else {
    tn = (long)blockIdx.y * BN; k0 = (long)blockIdx.z * Kchunk;
  }
  const int wm0 = (wave / WN) * (FM * 16);
  const int wn0 = (wave % WN) * (FN * 16);

  f32x4 acc[FM][FN] = {};

  constexpr int A_LOADS = (BM * BK) / (NT * 8);
  constexpr int B_LOADS = (BN * BK) / (NT * 8);

  for (int kt = 0; kt < Kchunk; kt += BK) {
    const long kb = k0 + kt;
#pragma unroll
    for (int i = 0; i < A_LOADS; ++i) {
      int s = (i * NT + tid) * 8;
      int row = s / BK, kk = s % BK;
      *(u16x8*)(&As[row * BK + (kk ^ ((row & 7) << 3))]) =
          *(const u16x8*)(A + (tm + row) * (long)lda + kb + kk);
    }
#pragma unroll
    for (int i = 0; i < B_LOADS; ++i) {
      int s = (i * NT + tid) * 8;
      int row = s / BK, kk = s % BK;
      *(u16x8*)(&Bs[row * BK + (kk ^ ((row & 7) << 3))]) =
          *(const u16x8*)(B + (tn + row) * (long)ldb + kb + kk);
    }
    __syncthreads();
#pragma unroll
    for (int kk = 0; kk < BK; kk += 32) {
      bf16x8 af[FM], bfr[FN];
#pragma unroll
      for (int i = 0; i < FM; ++i) {
        int ar = wm0 + i * 16 + (lane & 15);
        int ac = kk + (lane >> 4) * 8;
        af[i] = *(const bf16x8*)(&As[ar * BK + (ac ^ ((ar & 7) << 3))]);
      }
#pragma unroll
      for (int j = 0; j < FN; ++j) {
        int br = wn0 + j * 16 + (lane & 15);
        int bc = kk + (lane >> 4) * 8;
        bfr[j] = *(const bf16x8*)(&Bs[br * BK + (bc ^ ((br & 7) << 3))]);
      }
#pragma unroll
      for (int i = 0; i < FM; ++i)
#pragma unroll
        for (int j = 0; j < FN; ++j)
          acc[i][j] = __builtin_amdgcn_mfma_f32_16x16x32_bf16(af[i], bfr[j], acc[i][j], 0, 0, 0);
    }
    __syncthreads();
  }

#pragma unroll
  for (int i = 0; i < FM; ++i) {
#pragma unroll
    for (int j = 0; j < FN; ++j) {
      const long col = tn + wn0 + j * 16 + (lane & 15);
      float bv = 0.0f;
      if constexpr (BIAS) {
        if (MODE != 2 || blockIdx.z == 0) bv = bias[col];
      }
#pragma unroll
      for (int r = 0; r < 4; ++r) {
        const long row = tm + wm0 + i * 16 + (lane >> 4) * 4 + r;
        float v = acc[i][j][r] * scale + bv;
        if constexpr (MODE == 0) {
          ((float*)Cout)[cOff + row * (long)ldc + col] = v;
        } else if constexpr (MODE == 1) {
          ((u16*)Cout)[cOff + row * (long)ldc + col] = f2bf(v);
        } else if constexpr (MODE == 2) {
          atomicAdd(&((float*)Cout)[cOff + row * (long)ldc + col], v);
        } else {
          float ge = 0.5f * v * (1.0f + erff(v * 0.70710678118654752f));
          ((u16*)Cout)[cOff + row * (long)ldc + col] = f2bf(ge);
        }
      }
    }
  }
}

// ---------------- elementwise / reduction kernels ----------------

__global__ void conv_bf16(const float* __restrict__ src, int sld, int C,
                          u16* __restrict__ dst, int total) {
  int i = blockIdx.x * 256 + threadIdx.x;
  if (i >= total) return;
  if (sld == C) { dst[i] = f2bf(src[i]); return; }
  int r = i / C, c = i - r * C;
  dst[i] = f2bf(src[(size_t)r * sld + c]);
}

__global__ __launch_bounds__(1024) void transpose_bf16(const u16* __restrict__ src, int sld,
                                                       u16* __restrict__ dst, int dld) {
  __shared__ u16 tile[32][33];
  int r = blockIdx.y * 32 + threadIdx.y;
  int c = blockIdx.x * 32 + threadIdx.x;
  tile[threadIdx.y][threadIdx.x] = src[(size_t)r * sld + c];
  __syncthreads();
  int rr = blockIdx.x * 32 + threadIdx.y;
  int cc = blockIdx.y * 32 + threadIdx.x;
  dst[(size_t)rr * dld + cc] = tile[threadIdx.x][threadIdx.y];
}

__global__ void edge_kernel(const int* __restrict__ ei, float* __restrict__ S,
                            float* __restrict__ deg) {
  int e = blockIdx.x * 256 + threadIdx.x;
  int s = ei[e], d = ei[E_ + e];
  atomicAdd(&S[(size_t)d * N_ + s], 1.0f);
  atomicAdd(&deg[d], 1.0f);
}

__global__ __launch_bounds__(128) void ln12_kernel(const float* __restrict__ x,
    const float* __restrict__ g1, const float* __restrict__ b1,
    const float* __restrict__ g2, const float* __restrict__ b2,
    float* __restrict__ xn1, u16* __restrict__ xn1b, u16* __restrict__ xn2b)
{
  int row = blockIdx.x, t = threadIdx.x;
  size_t base = (size_t)row * D_ + t * 4;
  f32x4 v = *(const f32x4*)(x + base);
  float s = v[0] + v[1] + v[2] + v[3];
  float ss = v[0]*v[0] + v[1]*v[1] + v[2]*v[2] + v[3]*v[3];
  __shared__ float red[4];
  for (int off = 32; off; off >>= 1) { s += __shfl_down(s, off); ss += __shfl_down(ss, off); }
  if ((t & 63) == 0) { red[t >> 6] = s; red[2 + (t >> 6)] = ss; }
  __syncthreads();
  s = red[0] + red[1]; ss = red[2] + red[3];
  float mu = s * (1.0f / D_);
  float inv = rsqrtf(ss * (1.0f / D_) - mu * mu + 1e-5f);
#pragma unroll
  for (int i = 0; i < 4; ++i) {
    int c = t * 4 + i;
    float xh = (v[i] - mu) * inv;
    float o1 = xh * g1[c] + b1[c];
    float o2 = xh * g2[c] + b2[c];
    xn1[base + i] = o1;
    xn1b[base + i] = f2bf(o1);
    xn2b[base + i] = f2bf(o2);
  }
}

__global__ void finalize_aggr(const float* __restrict__ aggp, const float* __restrict__ part2,
                              const float* __restrict__ deg, const float* __restrict__ msg_b,
                              u16* __restrict__ aggrb) {
  int i = blockIdx.x * 256 + threadIdx.x;
  int n = i >> 9, d = i & 511;
  float dg = deg[n];
  float v = (aggp[i] + dg * (part2[i] + msg_b[d])) / fmaxf(dg, 1.0f);
  aggrb[i] = f2bf(v);
}

__global__ void gru_kernel(const float* __restrict__ gi, const float* __restrict__ gh,
                           const float* __restrict__ xn1, float* __restrict__ xm) {
  int i = blockIdx.x * 256 + threadIdx.x;
  int n = i >> 9, d = i & 511;
  size_t b = (size_t)n * TD_ + d;
  float ir = gi[b], iz = gi[b + 512], in_ = gi[b + 1024];
  float hr = gh[b], hz = gh[b + 512], hn = gh[b + 1024];
  float r = 1.0f / (1.0f + expf(-(ir + hr)));
  float z = 1.0f / (1.0f + expf(-(iz + hz)));
  float nn = tanhf(in_ + r * hn);
  xm[i] = (1.0f - z) * nn + z * xn1[i];
}

// all-heads softmax over one chunk row; writes head-mean attn exactly once
__global__ __launch_bounds__(256) void softmax_mh(u16* __restrict__ sc,
                                                  float* __restrict__ attn) {
  const int row = blockIdx.x, t = threadIdx.x;
  __shared__ float red[4];
  float am[16] = {};
  for (int h = 0; h < H_; ++h) {
    u16* wr = sc + (size_t)h * ((size_t)CM_ * N_) + (size_t)row * N_;
    float p[16];
    u16x8 v0 = *(const u16x8*)(wr + t * 16);
    u16x8 v1 = *(const u16x8*)(wr + t * 16 + 8);
#pragma unroll
    for (int i = 0; i < 8; ++i) { p[i] = bf2f(v0[i]); p[8 + i] = bf2f(v1[i]); }
    float mx = p[0];
#pragma unroll
    for (int i = 1; i < 16; ++i) mx = fmaxf(mx, p[i]);
    for (int off = 32; off; off >>= 1) mx = fmaxf(mx, __shfl_down(mx, off));
    if ((t & 63) == 0) red[t >> 6] = mx;
    __syncthreads();
    mx = fmaxf(fmaxf(red[0], red[1]), fmaxf(red[2], red[3]));
    __syncthreads();
    float sum = 0.0f;
#pragma unroll
    for (int i = 0; i < 16; ++i) { p[i] = expf(p[i] - mx); sum += p[i]; }
    for (int off = 32; off; off >>= 1) sum += __shfl_down(sum, off);
    if ((t & 63) == 0) red[t >> 6] = sum;
    __syncthreads();
    float inv = 1.0f / (red[0] + red[1] + red[2] + red[3]);
    __syncthreads();
#pragma unroll
    for (int i = 0; i < 16; ++i) {
      float wv = p[i] * inv;
      wr[t * 16 + i] = f2bf(wv);
      am[i] += 0.125f * wv;
    }
  }
  float* ar = attn + (size_t)row * N_ + t * 16;
#pragma unroll
  for (int i = 0; i < 16; ++i) ar[i] = am[i];
}

__global__ __launch_bounds__(64) void gate_kernel(const float* __restrict__ xm,
    const float* __restrict__ xa, const float* __restrict__ gw,
    const float* __restrict__ gb, float* __restrict__ g) {
  int n = blockIdx.x, l = threadIdx.x;
  const float* m = xm + (size_t)n * D_;
  const float* a = xa + (size_t)n * D_;
  float s = 0.0f;
  for (int j = l; j < D_; j += 64) s += m[j] * gw[j] + a[j] * gw[D_ + j];
  for (int off = 32; off; off >>= 1) s += __shfl_down(s, off);
  if (l == 0) g[n] = 1.0f / (1.0f + expf(-(s + gb[0])));
}

__global__ __launch_bounds__(128) void combine_ln3(const float* __restrict__ x,
    const float* __restrict__ xm, const float* __restrict__ xa, const float* __restrict__ g,
    const float* __restrict__ g3, const float* __restrict__ b3,
    float* __restrict__ xc, u16* __restrict__ xn3b)
{
  int row = blockIdx.x, t = threadIdx.x;
  size_t base = (size_t)row * D_ + t * 4;
  float gg = g[row];
  f32x4 xv = *(const f32x4*)(x + base);
  f32x4 mv = *(const f32x4*)(xm + base);
  f32x4 av = *(const f32x4*)(xa + base);
  f32x4 cv = xv + gg * mv + (1.0f - gg) * av;
  *(f32x4*)(xc + base) = cv;
  float s = cv[0] + cv[1] + cv[2] + cv[3];
  float ss = cv[0]*cv[0] + cv[1]*cv[1] + cv[2]*cv[2] + cv[3]*cv[3];
  __shared__ float red[4];
  for (int off = 32; off; off >>= 1) { s += __shfl_down(s, off); ss += __shfl_down(ss, off); }
  if ((t & 63) == 0) { red[t >> 6] = s; red[2 + (t >> 6)] = ss; }
  __syncthreads();
  s = red[0] + red[1]; ss = red[2] + red[3];
  float mu = s * (1.0f / D_);
  float inv = rsqrtf(ss * (1.0f / D_) - mu * mu + 1e-5f);
#pragma unroll
  for (int i = 0; i < 4; ++i) {
    int c = t * 4 + i;
    float xh = (cv[i] - mu) * inv;
    xn3b[base + i] = f2bf(xh * g3[c] + b3[c]);
  }
}

__global__ void final_add(const float* __restrict__ a, const float* __restrict__ b,
                          float* __restrict__ o) {
  size_t i = ((size_t)blockIdx.x * 256 + threadIdx.x) * 4;
  f32x4 va = *(const f32x4*)(a + i);
  f32x4 vb = *(const f32x4*)(b + i);
  *(f32x4*)(o + i) = va + vb;
}

// ------------------------------ launch ------------------------------

extern "C" void kernel_launch(void* const* d_in, const int* in_sizes, int n_in,
                              void* d_out, int out_size, void* d_ws, size_t ws_size,
                              hipStream_t stream)
{
  (void)in_sizes; (void)n_in; (void)out_size;
  const float* x         = (const float*)d_in[0];
  const int*   ei        = (const int*)d_in[1];
  const float* ln1_g     = (const float*)d_in[2];
  const float* ln1_b     = (const float*)d_in[3];
  const float* ln2_g     = (const float*)d_in[4];
  const float* ln2_b     = (const float*)d_in[5];
  const float* ln3_g     = (const float*)d_in[6];
  const float* ln3_b     = (const float*)d_in[7];
  const float* in_proj_w = (const float*)d_in[8];
  const float* in_proj_b = (const float*)d_in[9];
  const float* out_proj_w= (const float*)d_in[10];
  const float* out_proj_b= (const float*)d_in[11];
  const float* msg_w     = (const float*)d_in[12];
  const float* msg_b     = (const float*)d_in[13];
  const float* gru_wih   = (const float*)d_in[14];
  const float* gru_whh   = (const float*)d_in[15];
  const float* gru_bih   = (const float*)d_in[16];
  const float* gru_bhh   = (const float*)d_in[17];
  const float* ffn_w1    = (const float*)d_in[18];
  const float* ffn_b1    = (const float*)d_in[19];
  const float* ffn_w2    = (const float*)d_in[20];
  const float* ffn_b2    = (const float*)d_in[21];
  const float* gate_w    = (const float*)d_in[22];
  const float* gate_b    = (const float*)d_in[23];

  char* ws = (char*)d_ws;
  size_t o = 0;
  auto alloc = [&](size_t b) { size_t r = o; o += (b + 255) & ~(size_t)255; return r; };
  const size_t o_xn1   = alloc((size_t)N_ * D_ * 4);
  const size_t o_xn1b  = alloc((size_t)N_ * D_ * 2);
  const size_t o_xn2b  = alloc((size_t)N_ * D_ * 2);
  const size_t o_xn1T  = alloc((size_t)N_ * D_ * 2);
  const size_t o_ipb   = alloc((size_t)TD_ * D_ * 2);
  const size_t o_w1b   = alloc((size_t)D_ * D_ * 2);
  const size_t o_w2b   = alloc((size_t)D_ * D_ * 2);
  const size_t o_wihb  = alloc((size_t)TD_ * D_ * 2);
  const size_t o_whhb  = alloc((size_t)TD_ * D_ * 2);
  const size_t o_opb   = alloc((size_t)D_ * D_ * 2);
  const size_t o_f1b   = alloc((size_t)FD_ * D_ * 2);
  const size_t o_f2b   = alloc((size_t)D_ * FD_ * 2);
  const size_t o_deg   = alloc((size_t)N_ * 4);
  const size_t o_gv    = alloc((size_t)N_ * 4);
  const size_t o_part2 = alloc((size_t)N_ * D_ * 4);
  const size_t o_aggp  = alloc((size_t)N_ * D_ * 4);
  const size_t o_aggrb = alloc((size_t)N_ * D_ * 2);
  const size_t o_gsb   = alloc((size_t)N_ * D_ * 2);
  const size_t o_xm    = alloc((size_t)N_ * D_ * 4);
  const size_t o_xn3b  = alloc((size_t)N_ * D_ * 2);
  const size_t o_ctxb  = alloc((size_t)N_ * D_ * 2);
  const size_t o_big1  = alloc((size_t)N_ * N_ * 4);  // S f32 -> per-chunk all-head scores bf16
  const size_t o_big2  = alloc((size_t)N_ * N_ * 2);  // Sb    -> h1b
  const size_t o_rn    = alloc((size_t)N_ * TD_ * 4); // gatherf -> gi -> qkvb+vT+ctx
  const size_t o_ro    = alloc((size_t)N_ * TD_ * 4); // gh -> x_attn+xc+ffn2o
  if (ws_size < o) return;

  float* xn1  = (float*)(ws + o_xn1);
  u16* xn1b   = (u16*)(ws + o_xn1b);
  u16* xn2b   = (u16*)(ws + o_xn2b);
  u16* xn1T   = (u16*)(ws + o_xn1T);
  u16* ipb    = (u16*)(ws + o_ipb);
  u16* w1b    = (u16*)(ws + o_w1b);
  u16* w2b    = (u16*)(ws + o_w2b);
  u16* wihb   = (u16*)(ws + o_wihb);
  u16* whhb   = (u16*)(ws + o_whhb);
  u16* opb    = (u16*)(ws + o_opb);
  u16* f1b    = (u16*)(ws + o_f1b);
  u16* f2b    = (u16*)(ws + o_f2b);
  float* deg  = (float*)(ws + o_deg);
  float* gv   = (float*)(ws + o_gv);
  float* part2= (float*)(ws + o_part2);
  float* aggp = (float*)(ws + o_aggp);
  u16* aggrb  = (u16*)(ws + o_aggrb);
  u16* gsb    = (u16*)(ws + o_gsb);
  float* xm   = (float*)(ws + o_xm);
  u16* xn3b   = (u16*)(ws + o_xn3b);
  u16* ctxb   = (u16*)(ws + o_ctxb);
  float* Sf   = (float*)(ws + o_big1);
  u16* scc    = (u16*)(ws + o_big1);   // [H][CM_][N_] bf16 per chunk (67 MB)
  u16* Sb     = (u16*)(ws + o_big2);
  u16* h1b    = (u16*)(ws + o_big2);
  float* gatherf = (float*)(ws + o_rn);
  float* gi   = (float*)(ws + o_rn);
  u16* qkvb   = (u16*)(ws + o_rn);
  u16* vT     = (u16*)(ws + o_rn + (size_t)N_ * TD_ * 2);
  float* ctx  = (float*)(ws + o_rn + (size_t)N_ * TD_ * 2 + (size_t)D_ * N_ * 2);
  float* gh   = (float*)(ws + o_ro);
  float* xattn= (float*)(ws + o_ro);
  float* xc   = (float*)(ws + o_ro + (size_t)N_ * D_ * 4);
  float* ffn2o= (float*)(ws + o_ro + (size_t)N_ * D_ * 8);

  float* outp = (float*)d_out;
  float* attn = (float*)d_out + (size_t)N_ * D_;

  hipMemsetAsync(Sf, 0, (size_t)N_ * N_ * 4, stream);
  hipMemsetAsync(deg, 0, (size_t)N_ * 4, stream);

  // weight conversions to bf16
  conv_bf16<<<3072, 256, 0, stream>>>(in_proj_w, 512, 512, ipb, TD_ * D_);
  conv_bf16<<<3072, 256, 0, stream>>>(gru_wih, 512, 512, wihb, TD_ * D_);
  conv_bf16<<<3072, 256, 0, stream>>>(gru_whh, 512, 512, whhb, TD_ * D_);
  conv_bf16<<<1024, 256, 0, stream>>>(out_proj_w, 512, 512, opb, D_ * D_);
  conv_bf16<<<4096, 256, 0, stream>>>(ffn_w1, 512, 512, f1b, FD_ * D_);
  conv_bf16<<<4096, 256, 0, stream>>>(ffn_w2, 2048, 2048, f2b, D_ * FD_);
  conv_bf16<<<1024, 256, 0, stream>>>(msg_w, 1024, 512, w1b, D_ * D_);
  conv_bf16<<<1024, 256, 0, stream>>>(msg_w + 512, 1024, 512, w2b, D_ * D_);

  // LN1/LN2 (shared mean/var)
  ln12_kernel<<<N_, 128, 0, stream>>>(x, ln1_g, ln1_b, ln2_g, ln2_b, xn1, xn1b, xn2b);
  transpose_bf16<<<dim3(16, 128), dim3(32, 32), 0, stream>>>(xn1b, D_, xn1T, N_);

  // adjacency-count matrix + degree
  edge_kernel<<<512, 256, 0, stream>>>(ei, Sf, deg);
  conv_bf16<<<65536, 256, 0, stream>>>(Sf, N_, N_, Sb, N_ * N_);

  // gather_sum = S @ xn1  (split-K x4, fp32 atomics for parallelism)
  hipMemsetAsync(gatherf, 0, (size_t)N_ * D_ * 4, stream);
  gemm_bt<128, 64, 64, 4, 1, 2, 4, 2, false, 0><<<dim3(32, 8, 4), 256, 0, stream>>>(
      Sb, N_, xn1T, N_, gatherf, D_, nullptr, 1.0f, 1024, 0, 0, 0);
  conv_bf16<<<8192, 256, 0, stream>>>(gatherf, 512, 512, gsb, N_ * D_);
  // part2 = xn1 @ W2^T
  gemm_bt<128, 64, 64, 4, 1, 2, 4, 0, false, 0><<<dim3(32, 8), 256, 0, stream>>>(
      xn1b, D_, w2b, D_, part2, D_, nullptr, 1.0f, D_, 0, 0, 0);
  // aggr_pre = gather_sum @ W1^T
  gemm_bt<128, 64, 64, 4, 1, 2, 4, 0, false, 0><<<dim3(32, 8), 256, 0, stream>>>(
      gsb, D_, w1b, D_, aggp, D_, nullptr, 1.0f, D_, 0, 0, 0);
  finalize_aggr<<<8192, 256, 0, stream>>>(aggp, part2, deg, msg_b, aggrb);

  // GRU gates
  gemm_bt<128, 128, 64, 2, 2, 4, 4, 0, true, 0><<<dim3(32, 12), 256, 0, stream>>>(
      aggrb, D_, wihb, D_, gi, TD_, gru_bih, 1.0f, D_, 0, 0, 0);
  gemm_bt<128, 128, 64, 2, 2, 4, 4, 0, true, 0><<<dim3(32, 12), 256, 0, stream>>>(
      xn1b, D_, whhb, D_, gh, TD_, gru_bhh, 1.0f, D_, 0, 0, 0);
  gru_kernel<<<8192, 256, 0, stream>>>(gi, gh, xn1, xm);

  // attention: qkv projection (bf16 out, gi region now dead)
  gemm_bt<128, 128, 64, 2, 2, 4, 4, 1, true, 0><<<dim3(32, 12), 256, 0, stream>>>(
      xn2b, D_, ipb, D_, qkvb, TD_, in_proj_b, 1.0f, D_, 0, 0, 0);
  transpose_bf16<<<dim3(16, 128), dim3(32, 32), 0, stream>>>(qkvb + 1024, TD_, vT, N_);
  hipMemsetAsync(ctx, 0, (size_t)N_ * D_ * 4, stream);

  // chunked all-heads attention: scores -> all-head softmax (+mean) -> PV
  for (int c = 0; c < N_ / CM_; ++c) {
    gemm_bt<128, 128, 64, 2, 2, 4, 4, 1, false, 1><<<dim3(CM_ / 128, 32, 8), 256, 0, stream>>>(
        qkvb + (size_t)c * CM_ * TD_, TD_, qkvb + 512, TD_, scc, N_, nullptr,
        0.125f, 64, 64, 64, (size_t)CM_ * N_);
    softmax_mh<<<CM_, 256, 0, stream>>>(scc, attn + (size_t)c * CM_ * N_);
    gemm_bt<128, 64, 64, 4, 1, 2, 4, 2, false, 2><<<dim3(CM_ / 128, 8, 8), 256, 0, stream>>>(
        scc, N_, vT, N_, ctx + (size_t)c * CM_ * D_, D_, nullptr, 1.0f, 512,
        (size_t)CM_ * N_, (size_t)64 * N_, 64);
  }

  conv_bf16<<<8192, 256, 0, stream>>>(ctx, 512, 512, ctxb, N_ * D_);
  gemm_bt<128, 64, 64, 4, 1, 2, 4, 0, true, 0><<<dim3(32, 8), 256, 0, stream>>>(
      ctxb, D_, opb, D_, xattn, D_, out_proj_b, 1.0f, D_, 0, 0, 0);

  // gated combine + LN3
  gate_kernel<<<N_, 64, 0, stream>>>(xm, xattn, gate_w, gate_b, gv);
  combine_ln3<<<N_, 128, 0, stream>>>(x, xm, xattn, gv, ln3_g, ln3_b, xc, xn3b);

  // FFN (GELU fused into GEMM epilogue; FFN2 split-K x4)
  gemm_bt<128, 128, 64, 2, 2, 4, 4, 3, true, 0><<<dim3(32, 16), 256, 0, stream>>>(
      xn3b, D_, f1b, D_, h1b, FD_, ffn_b1, 1.0f, D_, 0, 0, 0);
  hipMemsetAsync(ffn2o, 0, (size_t)N_ * D_ * 4, stream);
  gemm_bt<128, 64, 64, 4, 1, 2, 4, 2, true, 0><<<dim3(32, 8, 4), 256, 0, stream>>>(
      h1b, FD_, f2b, FD_, ffn2o, D_, ffn_b2, 1.0f, 512, 0, 0, 0);
  final_add<<<2048, 256, 0, stream>>>(xc, ffn2o, outp);
}

// Round 4
// 675.905 us; speedup vs baseline: 1.8187x; 1.1369x over previous
//
#include <hip/hip_runtime.h>
#include <stdint.h>

#define N_ 4096
#define D_ 512
#define H_ 8
#define E_ 131072
#define TD_ 1536
#define FD_ 2048
#define CM_ 1024  // attention row-chunk

typedef unsigned short u16;
typedef __bf16 bf16x8 __attribute__((ext_vector_type(8)));
typedef u16 u16x8 __attribute__((ext_vector_type(8)));
typedef float f32x4 __attribute__((ext_vector_type(4)));

__device__ __forceinline__ u16 f2bf(float f) {
  union { float f; uint32_t u; } v; v.f = f;
  return (u16)((v.u + 0x7FFFu + ((v.u >> 16) & 1u)) >> 16);
}
__device__ __forceinline__ float bf2f(u16 b) {
  union { uint32_t u; float f; } v; v.u = ((uint32_t)b) << 16; return v.f;
}

// direct global->LDS DMA, 16B per lane; lptr must be wave-uniform base.
// Casts go through integers (CK-style) to satisfy clang address-space rules.
__device__ __forceinline__ void gload16(const u16* g, u16* l) {
  __builtin_amdgcn_global_load_lds(
      (const __attribute__((address_space(1))) void*)(uintptr_t)g,
      (__attribute__((address_space(3))) void*)(uint32_t)(uintptr_t)l, 16, 0, 0);
}

// ---------------- GEMM: C[M,N] = A[M,K] @ B[N,K]^T (+bias) -----------------
// MODE: 0 = f32 store, 1 = bf16 store (scale applied), 2 = f32 atomicAdd,
//       3 = exact-GELU then bf16 store
// HM (head mode): 0 = none (y = N-block, z = split-K)
//                 1 = z is head index (A/B/C shifted by hA/hB/hC, no split-K)
//                 2 = y is head index (N-block forced 0), z = split-K
// LDS layout: linear destination for global_load_lds; the XOR swizzle is
// applied to the per-lane global SOURCE column and to the read side (m173).
template <int BM, int BN, int BK, int WM, int WN, int FM, int FN, int MODE, bool BIAS, int HM>
__global__ __launch_bounds__(WM * WN * 64) void gemm_bt(
    const u16* __restrict__ A, int lda, const u16* __restrict__ B, int ldb,
    void* __restrict__ Cout, int ldc, const float* __restrict__ bias,
    float scale, int Kchunk, size_t hA, size_t hB, size_t hC)
{
  static_assert(BM == WM * FM * 16 && BN == WN * FN * 16, "tile shape");
  static_assert(BK == 64, "LDS swizzle assumes BK=64");
  __shared__ alignas(16) u16 As[BM * BK];
  __shared__ alignas(16) u16 Bs[BN * BK];
  constexpr int NT = WM * WN * 64;
  const int tid = threadIdx.x;
  const int lane = tid & 63;
  const int wave = tid >> 6;
  const long tm = (long)blockIdx.x * BM;
  long tn, k0;
  size_t cOff = 0;
  if constexpr (HM == 1) {
    A += (size_t)blockIdx.z * hA; B += (size_t)blockIdx.z * hB; cOff = (size_t)blockIdx.z * hC;
    tn = (long)blockIdx.y * BN; k0 = 0;
  } else if constexpr (HM == 2) {
    A += (size_t)blockIdx.y * hA; B += (size_t)blockIdx.y * hB; cOff = (size_t)blockIdx.y * hC;
    tn = 0; k0 = (long)blockIdx.z * Kchunk;
  } else {
    tn = (long)blockIdx.y * BN; k0 = (long)blockIdx.z * Kchunk;
  }
  const int wm0 = (wave / WN) * (FM * 16);
  const int wn0 = (wave % WN) * (FN * 16);

  f32x4 acc[FM][FN] = {};

  constexpr int A_LOADS = (BM * BK) / (NT * 8);
  constexpr int B_LOADS = (BN * BK) / (NT * 8);

  for (int kt = 0; kt < Kchunk; kt += BK) {
    const long kb = k0 + kt;
#pragma unroll
    for (int i = 0; i < A_LOADS; ++i) {
      int sB = (i * NT + wave * 64) * 8;     // wave-uniform LDS element base
      int s = sB + lane * 8;
      int row = s / BK;
      int blk = (s % BK) >> 3;
      gload16(A + (tm + row) * (long)lda + kb + ((blk ^ (row & 7)) << 3), As + sB);
    }
#pragma unroll
    for (int i = 0; i < B_LOADS; ++i) {
      int sB = (i * NT + wave * 64) * 8;
      int s = sB + lane * 8;
      int row = s / BK;
      int blk = (s % BK) >> 3;
      gload16(B + (tn + row) * (long)ldb + kb + ((blk ^ (row & 7)) << 3), Bs + sB);
    }
    __syncthreads();
#pragma unroll
    for (int kk = 0; kk < BK; kk += 32) {
      bf16x8 af[FM], bfr[FN];
#pragma unroll
      for (int i = 0; i < FM; ++i) {
        int ar = wm0 + i * 16 + (lane & 15);
        int ac = kk + (lane >> 4) * 8;
        af[i] = *(const bf16x8*)(&As[ar * BK + (ac ^ ((ar & 7) << 3))]);
      }
#pragma unroll
      for (int j = 0; j < FN; ++j) {
        int br = wn0 + j * 16 + (lane & 15);
        int bc = kk + (lane >> 4) * 8;
        bfr[j] = *(const bf16x8*)(&Bs[br * BK + (bc ^ ((br & 7) << 3))]);
      }
#pragma unroll
      for (int i = 0; i < FM; ++i)
#pragma unroll
        for (int j = 0; j < FN; ++j)
          acc[i][j] = __builtin_amdgcn_mfma_f32_16x16x32_bf16(af[i], bfr[j], acc[i][j], 0, 0, 0);
    }
    __syncthreads();
  }

#pragma unroll
  for (int i = 0; i < FM; ++i) {
#pragma unroll
    for (int j = 0; j < FN; ++j) {
      const long col = tn + wn0 + j * 16 + (lane & 15);
      float bv = 0.0f;
      if constexpr (BIAS) {
        if (MODE != 2 || blockIdx.z == 0) bv = bias[col];
      }
#pragma unroll
      for (int r = 0; r < 4; ++r) {
        const long row = tm + wm0 + i * 16 + (lane >> 4) * 4 + r;
        float v = acc[i][j][r] * scale + bv;
        if constexpr (MODE == 0) {
          ((float*)Cout)[cOff + row * (long)ldc + col] = v;
        } else if constexpr (MODE == 1) {
          ((u16*)Cout)[cOff + row * (long)ldc + col] = f2bf(v);
        } else if constexpr (MODE == 2) {
          atomicAdd(&((float*)Cout)[cOff + row * (long)ldc + col], v);
        } else {
          float ge = 0.5f * v * (1.0f + erff(v * 0.70710678118654752f));
          ((u16*)Cout)[cOff + row * (long)ldc + col] = f2bf(ge);
        }
      }
    }
  }
}

// ---------------- elementwise / reduction kernels ----------------

// single-dispatch conversion of all weight matrices to bf16 (msg_w split)
__global__ void conv_weights(const float* __restrict__ ip, const float* __restrict__ wih,
    const float* __restrict__ whh, const float* __restrict__ op,
    const float* __restrict__ f1, const float* __restrict__ f2, const float* __restrict__ mw,
    u16* __restrict__ ipb, u16* __restrict__ wihb, u16* __restrict__ whhb,
    u16* __restrict__ opb, u16* __restrict__ f1b, u16* __restrict__ f2b,
    u16* __restrict__ w1b, u16* __restrict__ w2b)
{
  int i = (blockIdx.x * 256 + threadIdx.x) * 4;
  if (i >= 5242880) return;
  if (i >= 4718592) {           // msg_w [512][1024] -> w1b | w2b
    int j = i - 4718592;
    int r = j >> 10, c = j & 1023;
    f32x4 v = *(const f32x4*)(mw + j);
    u16* d = (c < 512 ? w1b + r * 512 + c : w2b + r * 512 + (c - 512));
#pragma unroll
    for (int k = 0; k < 4; ++k) d[k] = f2bf(v[k]);
    return;
  }
  const float* src; u16* dst; int off;
  if      (i < 786432)  { src = ip;  dst = ipb;  off = i; }
  else if (i < 1572864) { src = wih; dst = wihb; off = i - 786432; }
  else if (i < 2359296) { src = whh; dst = whhb; off = i - 1572864; }
  else if (i < 2621440) { src = op;  dst = opb;  off = i - 2359296; }
  else if (i < 3670016) { src = f1;  dst = f1b;  off = i - 2621440; }
  else                  { src = f2;  dst = f2b;  off = i - 3670016; }
  f32x4 v = *(const f32x4*)(src + off);
#pragma unroll
  for (int k = 0; k < 4; ++k) dst[off + k] = f2bf(v[k]);
}

// contiguous f32 -> bf16, 4 elems/thread
__global__ void conv4_bf16(const float* __restrict__ src, u16* __restrict__ dst, int total4) {
  int i = blockIdx.x * 256 + threadIdx.x;
  if (i >= total4) return;
  f32x4 v = *(const f32x4*)(src + (size_t)i * 4);
  u16* d = dst + (size_t)i * 4;
#pragma unroll
  for (int k = 0; k < 4; ++k) d[k] = f2bf(v[k]);
}

__global__ __launch_bounds__(1024) void transpose_bf16(const u16* __restrict__ src, int sld,
                                                       u16* __restrict__ dst, int dld) {
  __shared__ u16 tile[32][33];
  int r = blockIdx.y * 32 + threadIdx.y;
  int c = blockIdx.x * 32 + threadIdx.x;
  tile[threadIdx.y][threadIdx.x] = src[(size_t)r * sld + c];
  __syncthreads();
  int rr = blockIdx.x * 32 + threadIdx.y;
  int cc = blockIdx.y * 32 + threadIdx.x;
  dst[(size_t)rr * dld + cc] = tile[threadIdx.x][threadIdx.y];
}

__global__ void edge_kernel(const int* __restrict__ ei, float* __restrict__ S,
                            float* __restrict__ deg) {
  int e = blockIdx.x * 256 + threadIdx.x;
  int s = ei[e], d = ei[E_ + e];
  atomicAdd(&S[(size_t)d * N_ + s], 1.0f);
  atomicAdd(&deg[d], 1.0f);
}

__global__ __launch_bounds__(128) void ln12_kernel(const float* __restrict__ x,
    const float* __restrict__ g1, const float* __restrict__ b1,
    const float* __restrict__ g2, const float* __restrict__ b2,
    float* __restrict__ xn1, u16* __restrict__ xn1b, u16* __restrict__ xn2b)
{
  int row = blockIdx.x, t = threadIdx.x;
  size_t base = (size_t)row * D_ + t * 4;
  f32x4 v = *(const f32x4*)(x + base);
  float s = v[0] + v[1] + v[2] + v[3];
  float ss = v[0]*v[0] + v[1]*v[1] + v[2]*v[2] + v[3]*v[3];
  __shared__ float red[4];
  for (int off = 32; off; off >>= 1) { s += __shfl_down(s, off); ss += __shfl_down(ss, off); }
  if ((t & 63) == 0) { red[t >> 6] = s; red[2 + (t >> 6)] = ss; }
  __syncthreads();
  s = red[0] + red[1]; ss = red[2] + red[3];
  float mu = s * (1.0f / D_);
  float inv = rsqrtf(ss * (1.0f / D_) - mu * mu + 1e-5f);
#pragma unroll
  for (int i = 0; i < 4; ++i) {
    int c = t * 4 + i;
    float xh = (v[i] - mu) * inv;
    float o1 = xh * g1[c] + b1[c];
    float o2 = xh * g2[c] + b2[c];
    xn1[base + i] = o1;
    xn1b[base + i] = f2bf(o1);
    xn2b[base + i] = f2bf(o2);
  }
}

__global__ void finalize_aggr(const float* __restrict__ aggp, const float* __restrict__ part2,
                              const float* __restrict__ deg, const float* __restrict__ msg_b,
                              u16* __restrict__ aggrb) {
  int i = blockIdx.x * 256 + threadIdx.x;
  int n = i >> 9, d = i & 511;
  float dg = deg[n];
  float v = (aggp[i] + dg * (part2[i] + msg_b[d])) / fmaxf(dg, 1.0f);
  aggrb[i] = f2bf(v);
}

__global__ void gru_kernel(const float* __restrict__ gi, const float* __restrict__ gh,
                           const float* __restrict__ xn1, float* __restrict__ xm) {
  int i = blockIdx.x * 256 + threadIdx.x;
  int n = i >> 9, d = i & 511;
  size_t b = (size_t)n * TD_ + d;
  float ir = gi[b], iz = gi[b + 512], in_ = gi[b + 1024];
  float hr = gh[b], hz = gh[b + 512], hn = gh[b + 1024];
  float r = 1.0f / (1.0f + expf(-(ir + hr)));
  float z = 1.0f / (1.0f + expf(-(iz + hz)));
  float nn = tanhf(in_ + r * hn);
  xm[i] = (1.0f - z) * nn + z * xn1[i];
}

// all-heads softmax over one chunk row; writes head-mean attn exactly once
__global__ __launch_bounds__(256) void softmax_mh(u16* __restrict__ sc,
                                                  float* __restrict__ attn) {
  const int row = blockIdx.x, t = threadIdx.x;
  __shared__ float red[4];
  float am[16] = {};
  for (int h = 0; h < H_; ++h) {
    u16* wr = sc + (size_t)h * ((size_t)CM_ * N_) + (size_t)row * N_;
    float p[16];
    u16x8 v0 = *(const u16x8*)(wr + t * 16);
    u16x8 v1 = *(const u16x8*)(wr + t * 16 + 8);
#pragma unroll
    for (int i = 0; i < 8; ++i) { p[i] = bf2f(v0[i]); p[8 + i] = bf2f(v1[i]); }
    float mx = p[0];
#pragma unroll
    for (int i = 1; i < 16; ++i) mx = fmaxf(mx, p[i]);
    for (int off = 32; off; off >>= 1) mx = fmaxf(mx, __shfl_down(mx, off));
    if ((t & 63) == 0) red[t >> 6] = mx;
    __syncthreads();
    mx = fmaxf(fmaxf(red[0], red[1]), fmaxf(red[2], red[3]));
    __syncthreads();
    float sum = 0.0f;
#pragma unroll
    for (int i = 0; i < 16; ++i) { p[i] = expf(p[i] - mx); sum += p[i]; }
    for (int off = 32; off; off >>= 1) sum += __shfl_down(sum, off);
    if ((t & 63) == 0) red[t >> 6] = sum;
    __syncthreads();
    float inv = 1.0f / (red[0] + red[1] + red[2] + red[3]);
    __syncthreads();
#pragma unroll
    for (int i = 0; i < 16; ++i) {
      float wv = p[i] * inv;
      wr[t * 16 + i] = f2bf(wv);
      am[i] += 0.125f * wv;
    }
  }
  float* ar = attn + (size_t)row * N_ + t * 16;
#pragma unroll
  for (int i = 0; i < 16; ++i) ar[i] = am[i];
}

__global__ __launch_bounds__(64) void gate_kernel(const float* __restrict__ xm,
    const float* __restrict__ xa, const float* __restrict__ gw,
    const float* __restrict__ gb, float* __restrict__ g) {
  int n = blockIdx.x, l = threadIdx.x;
  const float* m = xm + (size_t)n * D_;
  const float* a = xa + (size_t)n * D_;
  float s = 0.0f;
  for (int j = l; j < D_; j += 64) s += m[j] * gw[j] + a[j] * gw[D_ + j];
  for (int off = 32; off; off >>= 1) s += __shfl_down(s, off);
  if (l == 0) g[n] = 1.0f / (1.0f + expf(-(s + gb[0])));
}

__global__ __launch_bounds__(128) void combine_ln3(const float* __restrict__ x,
    const float* __restrict__ xm, const float* __restrict__ xa, const float* __restrict__ g,
    const float* __restrict__ g3, const float* __restrict__ b3,
    float* __restrict__ xc, u16* __restrict__ xn3b)
{
  int row = blockIdx.x, t = threadIdx.x;
  size_t base = (size_t)row * D_ + t * 4;
  float gg = g[row];
  f32x4 xv = *(const f32x4*)(x + base);
  f32x4 mv = *(const f32x4*)(xm + base);
  f32x4 av = *(const f32x4*)(xa + base);
  f32x4 cv = xv + gg * mv + (1.0f - gg) * av;
  *(f32x4*)(xc + base) = cv;
  float s = cv[0] + cv[1] + cv[2] + cv[3];
  float ss = cv[0]*cv[0] + cv[1]*cv[1] + cv[2]*cv[2] + cv[3]*cv[3];
  __shared__ float red[4];
  for (int off = 32; off; off >>= 1) { s += __shfl_down(s, off); ss += __shfl_down(ss, off); }
  if ((t & 63) == 0) { red[t >> 6] = s; red[2 + (t >> 6)] = ss; }
  __syncthreads();
  s = red[0] + red[1]; ss = red[2] + red[3];
  float mu = s * (1.0f / D_);
  float inv = rsqrtf(ss * (1.0f / D_) - mu * mu + 1e-5f);
#pragma unroll
  for (int i = 0; i < 4; ++i) {
    int c = t * 4 + i;
    float xh = (cv[i] - mu) * inv;
    xn3b[base + i] = f2bf(xh * g3[c] + b3[c]);
  }
}

__global__ void final_add(const float* __restrict__ a, const float* __restrict__ b,
                          float* __restrict__ o) {
  size_t i = ((size_t)blockIdx.x * 256 + threadIdx.x) * 4;
  f32x4 va = *(const f32x4*)(a + i);
  f32x4 vb = *(const f32x4*)(b + i);
  *(f32x4*)(o + i) = va + vb;
}

// ------------------------------ launch ------------------------------

extern "C" void kernel_launch(void* const* d_in, const int* in_sizes, int n_in,
                              void* d_out, int out_size, void* d_ws, size_t ws_size,
                              hipStream_t stream)
{
  (void)in_sizes; (void)n_in; (void)out_size;
  const float* x         = (const float*)d_in[0];
  const int*   ei        = (const int*)d_in[1];
  const float* ln1_g     = (const float*)d_in[2];
  const float* ln1_b     = (const float*)d_in[3];
  const float* ln2_g     = (const float*)d_in[4];
  const float* ln2_b     = (const float*)d_in[5];
  const float* ln3_g     = (const float*)d_in[6];
  const float* ln3_b     = (const float*)d_in[7];
  const float* in_proj_w = (const float*)d_in[8];
  const float* in_proj_b = (const float*)d_in[9];
  const float* out_proj_w= (const float*)d_in[10];
  const float* out_proj_b= (const float*)d_in[11];
  const float* msg_w     = (const float*)d_in[12];
  const float* msg_b     = (const float*)d_in[13];
  const float* gru_wih   = (const float*)d_in[14];
  const float* gru_whh   = (const float*)d_in[15];
  const float* gru_bih   = (const float*)d_in[16];
  const float* gru_bhh   = (const float*)d_in[17];
  const float* ffn_w1    = (const float*)d_in[18];
  const float* ffn_b1    = (const float*)d_in[19];
  const float* ffn_w2    = (const float*)d_in[20];
  const float* ffn_b2    = (const float*)d_in[21];
  const float* gate_w    = (const float*)d_in[22];
  const float* gate_b    = (const float*)d_in[23];

  char* ws = (char*)d_ws;
  size_t o = 0;
  auto alloc = [&](size_t b) { size_t r = o; o += (b + 255) & ~(size_t)255; return r; };
  const size_t o_xn1   = alloc((size_t)N_ * D_ * 4);
  const size_t o_xn1b  = alloc((size_t)N_ * D_ * 2);
  const size_t o_xn2b  = alloc((size_t)N_ * D_ * 2);
  const size_t o_xn1T  = alloc((size_t)N_ * D_ * 2);
  const size_t o_ipb   = alloc((size_t)TD_ * D_ * 2);
  const size_t o_w1b   = alloc((size_t)D_ * D_ * 2);
  const size_t o_w2b   = alloc((size_t)D_ * D_ * 2);
  const size_t o_wihb  = alloc((size_t)TD_ * D_ * 2);
  const size_t o_whhb  = alloc((size_t)TD_ * D_ * 2);
  const size_t o_opb   = alloc((size_t)D_ * D_ * 2);
  const size_t o_f1b   = alloc((size_t)FD_ * D_ * 2);
  const size_t o_f2b   = alloc((size_t)D_ * FD_ * 2);
  const size_t o_deg   = alloc((size_t)N_ * 4);
  const size_t o_gv    = alloc((size_t)N_ * 4);
  const size_t o_part2 = alloc((size_t)N_ * D_ * 4);
  const size_t o_aggp  = alloc((size_t)N_ * D_ * 4);
  const size_t o_aggrb = alloc((size_t)N_ * D_ * 2);
  const size_t o_gsb   = alloc((size_t)N_ * D_ * 2);
  const size_t o_xm    = alloc((size_t)N_ * D_ * 4);
  const size_t o_xn3b  = alloc((size_t)N_ * D_ * 2);
  const size_t o_ctxb  = alloc((size_t)N_ * D_ * 2);
  const size_t o_big1  = alloc((size_t)N_ * N_ * 4);  // S f32 -> per-chunk all-head scores bf16
  const size_t o_big2  = alloc((size_t)N_ * N_ * 2);  // Sb    -> h1b
  const size_t o_rn    = alloc((size_t)N_ * TD_ * 4); // gi -> qkvb+vT+ctx
  const size_t o_ro    = alloc((size_t)N_ * TD_ * 4); // gh -> x_attn+xc+ffn2o
  if (ws_size < o) return;

  float* xn1  = (float*)(ws + o_xn1);
  u16* xn1b   = (u16*)(ws + o_xn1b);
  u16* xn2b   = (u16*)(ws + o_xn2b);
  u16* xn1T   = (u16*)(ws + o_xn1T);
  u16* ipb    = (u16*)(ws + o_ipb);
  u16* w1b    = (u16*)(ws + o_w1b);
  u16* w2b    = (u16*)(ws + o_w2b);
  u16* wihb   = (u16*)(ws + o_wihb);
  u16* whhb   = (u16*)(ws + o_whhb);
  u16* opb    = (u16*)(ws + o_opb);
  u16* f1b    = (u16*)(ws + o_f1b);
  u16* f2b    = (u16*)(ws + o_f2b);
  float* deg  = (float*)(ws + o_deg);
  float* gv   = (float*)(ws + o_gv);
  float* part2= (float*)(ws + o_part2);
  float* aggp = (float*)(ws + o_aggp);
  u16* aggrb  = (u16*)(ws + o_aggrb);
  u16* gsb    = (u16*)(ws + o_gsb);
  float* xm   = (float*)(ws + o_xm);
  u16* xn3b   = (u16*)(ws + o_xn3b);
  u16* ctxb   = (u16*)(ws + o_ctxb);
  float* Sf   = (float*)(ws + o_big1);
  u16* scc    = (u16*)(ws + o_big1);   // [H][CM_][N_] bf16 per chunk (67 MB)
  u16* Sb     = (u16*)(ws + o_big2);
  u16* h1b    = (u16*)(ws + o_big2);
  float* gi   = (float*)(ws + o_rn);
  u16* qkvb   = (u16*)(ws + o_rn);
  u16* vT     = (u16*)(ws + o_rn + (size_t)N_ * TD_ * 2);
  float* ctx  = (float*)(ws + o_rn + (size_t)N_ * TD_ * 2 + (size_t)D_ * N_ * 2);
  float* gh   = (float*)(ws + o_ro);
  float* xattn= (float*)(ws + o_ro);
  float* xc   = (float*)(ws + o_ro + (size_t)N_ * D_ * 4);
  float* ffn2o= (float*)(ws + o_ro + (size_t)N_ * D_ * 8);

  float* outp = (float*)d_out;
  float* attn = (float*)d_out + (size_t)N_ * D_;

  hipMemsetAsync(Sf, 0, (size_t)N_ * N_ * 4, stream);
  hipMemsetAsync(deg, 0, (size_t)N_ * 4, stream);

  // all weight conversions in one dispatch
  conv_weights<<<5120, 256, 0, stream>>>(in_proj_w, gru_wih, gru_whh, out_proj_w,
                                         ffn_w1, ffn_w2, msg_w,
                                         ipb, wihb, whhb, opb, f1b, f2b, w1b, w2b);

  // LN1/LN2 (shared mean/var)
  ln12_kernel<<<N_, 128, 0, stream>>>(x, ln1_g, ln1_b, ln2_g, ln2_b, xn1, xn1b, xn2b);
  transpose_bf16<<<dim3(16, 128), dim3(32, 32), 0, stream>>>(xn1b, D_, xn1T, N_);

  // adjacency-count matrix + degree
  edge_kernel<<<512, 256, 0, stream>>>(ei, Sf, deg);
  conv4_bf16<<<16384, 256, 0, stream>>>(Sf, Sb, N_ * N_ / 4);

  // gather_sum = S @ xn1  (64x64 tiles -> 512 blocks, bf16 out, no split-K)
  gemm_bt<64, 64, 64, 2, 2, 2, 2, 1, false, 0><<<dim3(64, 8), 256, 0, stream>>>(
      Sb, N_, xn1T, N_, gsb, D_, nullptr, 1.0f, N_, 0, 0, 0);
  // part2 = xn1 @ W2^T
  gemm_bt<64, 64, 64, 2, 2, 2, 2, 0, false, 0><<<dim3(64, 8), 256, 0, stream>>>(
      xn1b, D_, w2b, D_, part2, D_, nullptr, 1.0f, D_, 0, 0, 0);
  // aggr_pre = gather_sum @ W1^T
  gemm_bt<64, 64, 64, 2, 2, 2, 2, 0, false, 0><<<dim3(64, 8), 256, 0, stream>>>(
      gsb, D_, w1b, D_, aggp, D_, nullptr, 1.0f, D_, 0, 0, 0);
  finalize_aggr<<<8192, 256, 0, stream>>>(aggp, part2, deg, msg_b, aggrb);

  // GRU gates (64x128 tiles -> 768 blocks each)
  gemm_bt<64, 128, 64, 2, 2, 2, 4, 0, true, 0><<<dim3(64, 12), 256, 0, stream>>>(
      aggrb, D_, wihb, D_, gi, TD_, gru_bih, 1.0f, D_, 0, 0, 0);
  gemm_bt<64, 128, 64, 2, 2, 2, 4, 0, true, 0><<<dim3(64, 12), 256, 0, stream>>>(
      xn1b, D_, whhb, D_, gh, TD_, gru_bhh, 1.0f, D_, 0, 0, 0);
  gru_kernel<<<8192, 256, 0, stream>>>(gi, gh, xn1, xm);

  // attention: qkv projection (bf16 out, gi region now dead)
  gemm_bt<64, 128, 64, 2, 2, 2, 4, 1, true, 0><<<dim3(64, 12), 256, 0, stream>>>(
      xn2b, D_, ipb, D_, qkvb, TD_, in_proj_b, 1.0f, D_, 0, 0, 0);
  transpose_bf16<<<dim3(16, 128), dim3(32, 32), 0, stream>>>(qkvb + 1024, TD_, vT, N_);
  hipMemsetAsync(ctx, 0, (size_t)N_ * D_ * 4, stream);

  // chunked all-heads attention: scores -> all-head softmax (+mean) -> PV
  for (int c = 0; c < N_ / CM_; ++c) {
    gemm_bt<128, 128, 64, 2, 2, 4, 4, 1, false, 1><<<dim3(CM_ / 128, 32, 8), 256, 0, stream>>>(
        qkvb + (size_t)c * CM_ * TD_, TD_, qkvb + 512, TD_, scc, N_, nullptr,
        0.125f, 64, 64, 64, (size_t)CM_ * N_);
    softmax_mh<<<CM_, 256, 0, stream>>>(scc, attn + (size_t)c * CM_ * N_);
    gemm_bt<64, 64, 64, 2, 2, 2, 2, 2, false, 2><<<dim3(CM_ / 64, 8, 4), 256, 0, stream>>>(
        scc, N_, vT, N_, ctx + (size_t)c * CM_ * D_, D_, nullptr, 1.0f, 1024,
        (size_t)CM_ * N_, (size_t)64 * N_, 64);
  }

  conv4_bf16<<<2048, 256, 0, stream>>>(ctx, ctxb, N_ * D_ / 4);
  gemm_bt<64, 64, 64, 2, 2, 2, 2, 0, true, 0><<<dim3(64, 8), 256, 0, stream>>>(
      ctxb, D_, opb, D_, xattn, D_, out_proj_b, 1.0f, D_, 0, 0, 0);

  // gated combine + LN3
  gate_kernel<<<N_, 64, 0, stream>>>(xm, xattn, gate_w, gate_b, gv);
  combine_ln3<<<N_, 128, 0, stream>>>(x, xm, xattn, gv, ln3_g, ln3_b, xc, xn3b);

  // FFN (GELU fused into GEMM epilogue; FFN2 full-K, no atomics)
  gemm_bt<64, 128, 64, 2, 2, 2, 4, 3, true, 0><<<dim3(64, 16), 256, 0, stream>>>(
      xn3b, D_, f1b, D_, h1b, FD_, ffn_b1, 1.0f, D_, 0, 0, 0);
  gemm_bt<64, 64, 64, 2, 2, 2, 2, 0, true, 0><<<dim3(64, 8), 256, 0, stream>>>(
      h1b, FD_, f2b, FD_, ffn2o, D_, ffn_b2, 1.0f, FD_, 0, 0, 0);
  final_add<<<2048, 256, 0, stream>>>(xc, ffn2o, outp);
}

// Round 5
// 655.420 us; speedup vs baseline: 1.8756x; 1.0313x over previous
//
#include <hip/hip_runtime.h>
#include <stdint.h>

#define N_ 4096
#define D_ 512
#define H_ 8
#define E_ 131072
#define TD_ 1536
#define FD_ 2048
#define CM_ 1024  // attention row-chunk

typedef unsigned short u16;
typedef __bf16 bf16x8 __attribute__((ext_vector_type(8)));
typedef u16 u16x8 __attribute__((ext_vector_type(8)));
typedef float f32x4 __attribute__((ext_vector_type(4)));

__device__ __forceinline__ u16 f2bf(float f) {
  union { float f; uint32_t u; } v; v.f = f;
  return (u16)((v.u + 0x7FFFu + ((v.u >> 16) & 1u)) >> 16);
}
__device__ __forceinline__ float bf2f(u16 b) {
  union { uint32_t u; float f; } v; v.u = ((uint32_t)b) << 16; return v.f;
}

__device__ __forceinline__ void gload16(const u16* g, u16* l) {
  __builtin_amdgcn_global_load_lds(
      (const __attribute__((address_space(1))) void*)(uintptr_t)g,
      (__attribute__((address_space(3))) void*)(uint32_t)(uintptr_t)l, 16, 0, 0);
}

// ---------------- GEMM: C[M,N] = A[M,K] @ B[N,K]^T (+bias) -----------------
// MODE: 0 = f32 store, 1 = bf16 store (scale applied), 2 = f32 atomicAdd,
//       3 = exact-GELU then bf16 store, 4 = f32 store of (v + aux[row*ldc+col])
// HM: 0 = none (y = N-block, z = split-K)
//     1 = z is head (A/B/C shifted by hA/hB/hC), no split-K
//     2 = y is head (N-block forced 0), z = split-K
// AMODE: 0 = A bf16 via global_load_lds (source-swizzled)
//        1 = A bf16 scores -> P = exp(s - rowm)*rowinv  (reg-staged, swizzled write)
//        2 = A is f32, cast to bf16 (reg-staged, swizzled write)
template <int BM, int BN, int BK, int WM, int WN, int FM, int FN, int MODE, bool BIAS,
          int HM, int AMODE>
__global__ __launch_bounds__(WM * WN * 64) void gemm_bt(
    const u16* __restrict__ A, int lda, const u16* __restrict__ B, int ldb,
    void* __restrict__ Cout, int ldc, const float* __restrict__ bias,
    float scale, int Kchunk, size_t hA, size_t hB, size_t hC,
    const float* __restrict__ rowm, const float* __restrict__ rowinv)
{
  static_assert(BM == WM * FM * 16 && BN == WN * FN * 16, "tile shape");
  static_assert(BK == 64, "LDS swizzle assumes BK=64");
  __shared__ alignas(16) u16 As[BM * BK];
  __shared__ alignas(16) u16 Bs[BN * BK];
  constexpr int NT = WM * WN * 64;
  const int tid = threadIdx.x;
  const int lane = tid & 63;
  const int wave = tid >> 6;
  const long tm = (long)blockIdx.x * BM;
  long tn, k0;
  size_t cOff = 0;
  if constexpr (HM == 1) {
    A += (size_t)blockIdx.z * hA; B += (size_t)blockIdx.z * hB; cOff = (size_t)blockIdx.z * hC;
    tn = (long)blockIdx.y * BN; k0 = 0;
  } else if constexpr (HM == 2) {
    A += (size_t)blockIdx.y * hA; B += (size_t)blockIdx.y * hB; cOff = (size_t)blockIdx.y * hC;
    tn = 0; k0 = (long)blockIdx.z * Kchunk;
  } else {
    tn = (long)blockIdx.y * BN; k0 = (long)blockIdx.z * Kchunk;
  }
  const int wm0 = (wave / WN) * (FM * 16);
  const int wn0 = (wave % WN) * (FN * 16);

  f32x4 acc[FM][FN] = {};

  constexpr int A_LOADS = (BM * BK) / (NT * 8);
  constexpr int B_LOADS = (BN * BK) / (NT * 8);

  for (int kt = 0; kt < Kchunk; kt += BK) {
    const long kb = k0 + kt;
#pragma unroll
    for (int i = 0; i < A_LOADS; ++i) {
      if constexpr (AMODE == 0) {
        int sB = (i * NT + wave * 64) * 8;
        int s = sB + lane * 8;
        int row = s / BK;
        int blk = (s % BK) >> 3;
        gload16(A + (tm + row) * (long)lda + kb + ((blk ^ (row & 7)) << 3), As + sB);
      } else if constexpr (AMODE == 1) {
        int s = (i * NT + tid) * 8;
        int row = s / BK, kk = s % BK;
        u16x8 v = *(const u16x8*)(A + (tm + row) * (long)lda + kb + kk);
        int ridx = (int)blockIdx.y * CM_ + (int)tm + row;
        float m = rowm[ridx], iv = rowinv[ridx];
        u16x8 w;
#pragma unroll
        for (int k = 0; k < 8; ++k) w[k] = f2bf(expf(bf2f(v[k]) - m) * iv);
        *(u16x8*)(&As[row * BK + (kk ^ ((row & 7) << 3))]) = w;
      } else {
        int s = (i * NT + tid) * 8;
        int row = s / BK, kk = s % BK;
        const float* Af = (const float*)A;
        f32x4 lo = *(const f32x4*)(Af + (tm + row) * (long)lda + kb + kk);
        f32x4 hi = *(const f32x4*)(Af + (tm + row) * (long)lda + kb + kk + 4);
        u16x8 w;
#pragma unroll
        for (int k = 0; k < 4; ++k) { w[k] = f2bf(lo[k]); w[4 + k] = f2bf(hi[k]); }
        *(u16x8*)(&As[row * BK + (kk ^ ((row & 7) << 3))]) = w;
      }
    }
#pragma unroll
    for (int i = 0; i < B_LOADS; ++i) {
      int sB = (i * NT + wave * 64) * 8;
      int s = sB + lane * 8;
      int row = s / BK;
      int blk = (s % BK) >> 3;
      gload16(B + (tn + row) * (long)ldb + kb + ((blk ^ (row & 7)) << 3), Bs + sB);
    }
    __syncthreads();
#pragma unroll
    for (int kk = 0; kk < BK; kk += 32) {
      bf16x8 af[FM], bfr[FN];
#pragma unroll
      for (int i = 0; i < FM; ++i) {
        int ar = wm0 + i * 16 + (lane & 15);
        int ac = kk + (lane >> 4) * 8;
        af[i] = *(const bf16x8*)(&As[ar * BK + (ac ^ ((ar & 7) << 3))]);
      }
#pragma unroll
      for (int j = 0; j < FN; ++j) {
        int br = wn0 + j * 16 + (lane & 15);
        int bc = kk + (lane >> 4) * 8;
        bfr[j] = *(const bf16x8*)(&Bs[br * BK + (bc ^ ((br & 7) << 3))]);
      }
#pragma unroll
      for (int i = 0; i < FM; ++i)
#pragma unroll
        for (int j = 0; j < FN; ++j)
          acc[i][j] = __builtin_amdgcn_mfma_f32_16x16x32_bf16(af[i], bfr[j], acc[i][j], 0, 0, 0);
    }
    __syncthreads();
  }

#pragma unroll
  for (int i = 0; i < FM; ++i) {
#pragma unroll
    for (int j = 0; j < FN; ++j) {
      const long col = tn + wn0 + j * 16 + (lane & 15);
      float bv = 0.0f;
      if constexpr (BIAS) {
        if (MODE != 2 || blockIdx.z == 0) bv = bias[col];
      }
#pragma unroll
      for (int r = 0; r < 4; ++r) {
        const long row = tm + wm0 + i * 16 + (lane >> 4) * 4 + r;
        float v = acc[i][j][r] * scale + bv;
        if constexpr (MODE == 0) {
          ((float*)Cout)[cOff + row * (long)ldc + col] = v;
        } else if constexpr (MODE == 1) {
          ((u16*)Cout)[cOff + row * (long)ldc + col] = f2bf(v);
        } else if constexpr (MODE == 2) {
          atomicAdd(&((float*)Cout)[cOff + row * (long)ldc + col], v);
        } else if constexpr (MODE == 3) {
          float ge = 0.5f * v * (1.0f + erff(v * 0.70710678118654752f));
          ((u16*)Cout)[cOff + row * (long)ldc + col] = f2bf(ge);
        } else {
          ((float*)Cout)[cOff + row * (long)ldc + col] = v + rowm[row * (long)ldc + col];
        }
      }
    }
  }
}

// ---------------- elementwise / CSR / reduction kernels ----------------

// all weight conversions + concatenated GRU-hh bias in one dispatch
__global__ void conv_weights(const float* __restrict__ ip, const float* __restrict__ wih,
    const float* __restrict__ whh, const float* __restrict__ op,
    const float* __restrict__ f1, const float* __restrict__ f2, const float* __restrict__ mw,
    const float* __restrict__ gbhh,
    u16* __restrict__ ipb, u16* __restrict__ wihb, u16* __restrict__ whhb,
    u16* __restrict__ opb, u16* __restrict__ f1b, u16* __restrict__ f2b,
    u16* __restrict__ w1b, u16* __restrict__ w2b, float* __restrict__ biascat)
{
  int i = (blockIdx.x * 256 + threadIdx.x) * 4;
  if (i >= 5244928) return;
  if (i >= 5242880) {           // biascat[2048] = [gru_bhh | 0]
    int j = i - 5242880;
#pragma unroll
    for (int k = 0; k < 4; ++k) biascat[j + k] = (j + k < TD_) ? gbhh[j + k] : 0.0f;
    return;
  }
  if (i >= 4718592) {           // msg_w [512][1024] -> w1b | w2b
    int j = i - 4718592;
    int r = j >> 10, c = j & 1023;
    f32x4 v = *(const f32x4*)(mw + j);
    u16* d = (c < 512 ? w1b + r * 512 + c : w2b + r * 512 + (c - 512));
#pragma unroll
    for (int k = 0; k < 4; ++k) d[k] = f2bf(v[k]);
    return;
  }
  const float* src; u16* dst; int off;
  if      (i < 786432)  { src = ip;  dst = ipb;  off = i; }
  else if (i < 1572864) { src = wih; dst = wihb; off = i - 786432; }
  else if (i < 2359296) { src = whh; dst = whhb; off = i - 1572864; }
  else if (i < 2621440) { src = op;  dst = opb;  off = i - 2359296; }
  else if (i < 3670016) { src = f1;  dst = f1b;  off = i - 2621440; }
  else                  { src = f2;  dst = f2b;  off = i - 3670016; }
  f32x4 v = *(const f32x4*)(src + off);
#pragma unroll
  for (int k = 0; k < 4; ++k) dst[off + k] = f2bf(v[k]);
}

__global__ __launch_bounds__(1024) void transpose_bf16(const u16* __restrict__ src, int sld,
                                                       u16* __restrict__ dst, int dld) {
  __shared__ u16 tile[32][33];
  int r = blockIdx.y * 32 + threadIdx.y;
  int c = blockIdx.x * 32 + threadIdx.x;
  tile[threadIdx.y][threadIdx.x] = src[(size_t)r * sld + c];
  __syncthreads();
  int rr = blockIdx.x * 32 + threadIdx.y;
  int cc = blockIdx.y * 32 + threadIdx.x;
  dst[(size_t)rr * dld + cc] = tile[threadIdx.x][threadIdx.y];
}

__global__ void hist_kernel(const int* __restrict__ ei, int* __restrict__ degi) {
  int e = blockIdx.x * 256 + threadIdx.x;
  atomicAdd(&degi[ei[E_ + e]], 1);
}

__global__ __launch_bounds__(1024) void scan_kernel(const int* __restrict__ degi,
    int* __restrict__ rowstart, int* __restrict__ cursor) {
  __shared__ int sums[1024];
  int t = threadIdx.x;
  int b = t * 4;
  int d0 = degi[b], d1 = degi[b + 1], d2 = degi[b + 2], d3 = degi[b + 3];
  int tot = d0 + d1 + d2 + d3;
  sums[t] = tot;
  __syncthreads();
  for (int off = 1; off < 1024; off <<= 1) {
    int v = (t >= off) ? sums[t - off] : 0;
    __syncthreads();
    sums[t] += v;
    __syncthreads();
  }
  int excl = (t > 0) ? sums[t - 1] : 0;
  int p0 = excl, p1 = excl + d0, p2 = excl + d0 + d1, p3 = excl + d0 + d1 + d2;
  rowstart[b] = p0; rowstart[b + 1] = p1; rowstart[b + 2] = p2; rowstart[b + 3] = p3;
  cursor[b] = p0; cursor[b + 1] = p1; cursor[b + 2] = p2; cursor[b + 3] = p3;
  if (t == 1023) rowstart[N_] = excl + tot;
}

__global__ void scatter_kernel(const int* __restrict__ ei, int* __restrict__ cursor,
                               int* __restrict__ ss) {
  int e = blockIdx.x * 256 + threadIdx.x;
  int d = ei[E_ + e];
  int pos = atomicAdd(&cursor[d], 1);
  ss[pos] = ei[e];
}

// per-dst gather-sum of xn1 rows (f32 exact), bf16 out
__global__ __launch_bounds__(128) void gather_kernel(const int* __restrict__ rs,
    const int* __restrict__ ss, const float* __restrict__ xn1, u16* __restrict__ gsb) {
  int dst = blockIdx.x, t = threadIdx.x;
  int s0 = rs[dst], s1 = rs[dst + 1];
  __shared__ int sl[128];
  f32x4 acc = {0.0f, 0.0f, 0.0f, 0.0f};
  for (int base = s0; base < s1; base += 128) {
    int n = min(128, s1 - base);
    if (t < n) sl[t] = ss[base + t];
    __syncthreads();
    for (int j = 0; j < n; ++j)
      acc += *(const f32x4*)(xn1 + (size_t)sl[j] * D_ + t * 4);
    __syncthreads();
  }
  u16* dp = gsb + (size_t)dst * D_ + t * 4;
#pragma unroll
  for (int k = 0; k < 4; ++k) dp[k] = f2bf(acc[k]);
}

__global__ __launch_bounds__(128) void ln12_kernel(const float* __restrict__ x,
    const float* __restrict__ g1, const float* __restrict__ b1,
    const float* __restrict__ g2, const float* __restrict__ b2,
    float* __restrict__ xn1, u16* __restrict__ xn1b, u16* __restrict__ xn2b)
{
  int row = blockIdx.x, t = threadIdx.x;
  size_t base = (size_t)row * D_ + t * 4;
  f32x4 v = *(const f32x4*)(x + base);
  float s = v[0] + v[1] + v[2] + v[3];
  float ss = v[0]*v[0] + v[1]*v[1] + v[2]*v[2] + v[3]*v[3];
  __shared__ float red[4];
  for (int off = 32; off; off >>= 1) { s += __shfl_down(s, off); ss += __shfl_down(ss, off); }
  if ((t & 63) == 0) { red[t >> 6] = s; red[2 + (t >> 6)] = ss; }
  __syncthreads();
  s = red[0] + red[1]; ss = red[2] + red[3];
  float mu = s * (1.0f / D_);
  float inv = rsqrtf(ss * (1.0f / D_) - mu * mu + 1e-5f);
#pragma unroll
  for (int i = 0; i < 4; ++i) {
    int c = t * 4 + i;
    float xh = (v[i] - mu) * inv;
    float o1 = xh * g1[c] + b1[c];
    float o2 = xh * g2[c] + b2[c];
    xn1[base + i] = o1;
    xn1b[base + i] = f2bf(o1);
    xn2b[base + i] = f2bf(o2);
  }
}

// aggr = (aggp + deg*(part2 + msg_b)) / max(deg,1); part2 lives in ghp cols 1536..2047
__global__ void finalize_aggr(const float* __restrict__ aggp, const float* __restrict__ ghp,
                              const int* __restrict__ degi, const float* __restrict__ msg_b,
                              u16* __restrict__ aggrb) {
  int i = blockIdx.x * 256 + threadIdx.x;
  int n = i >> 9, d = i & 511;
  float dg = (float)degi[n];
  float p2 = ghp[(size_t)n * 2048 + 1536 + d];
  float v = (aggp[i] + dg * (p2 + msg_b[d])) / fmaxf(dg, 1.0f);
  aggrb[i] = f2bf(v);
}

__global__ void gru_kernel(const float* __restrict__ gi, const float* __restrict__ ghp,
                           const float* __restrict__ xn1, float* __restrict__ xm) {
  int i = blockIdx.x * 256 + threadIdx.x;
  int n = i >> 9, d = i & 511;
  size_t bi = (size_t)n * TD_ + d;
  size_t bh = (size_t)n * 2048 + d;
  float ir = gi[bi], iz = gi[bi + 512], in_ = gi[bi + 1024];
  float hr = ghp[bh], hz = ghp[bh + 512], hn = ghp[bh + 1024];
  float r = 1.0f / (1.0f + expf(-(ir + hr)));
  float z = 1.0f / (1.0f + expf(-(iz + hz)));
  float nn = tanhf(in_ + r * hn);
  xm[i] = (1.0f - z) * nn + z * xn1[i];
}

// all-heads softmax stats over one chunk row: writes rowm/rowinv + head-mean attn.
// scores are NOT rewritten; PV recomputes P from them.
__global__ __launch_bounds__(256) void softmax_mh(const u16* __restrict__ sc,
    float* __restrict__ attn, float* __restrict__ rowm, float* __restrict__ rowinv) {
  const int row = blockIdx.x, t = threadIdx.x;
  __shared__ float red[4];
  float am[16] = {};
  for (int h = 0; h < H_; ++h) {
    const u16* wr = sc + (size_t)h * ((size_t)CM_ * N_) + (size_t)row * N_;
    float p[16];
    u16x8 v0 = *(const u16x8*)(wr + t * 16);
    u16x8 v1 = *(const u16x8*)(wr + t * 16 + 8);
#pragma unroll
    for (int i = 0; i < 8; ++i) { p[i] = bf2f(v0[i]); p[8 + i] = bf2f(v1[i]); }
    float mx = p[0];
#pragma unroll
    for (int i = 1; i < 16; ++i) mx = fmaxf(mx, p[i]);
    for (int off = 32; off; off >>= 1) mx = fmaxf(mx, __shfl_down(mx, off));
    if ((t & 63) == 0) red[t >> 6] = mx;
    __syncthreads();
    mx = fmaxf(fmaxf(red[0], red[1]), fmaxf(red[2], red[3]));
    __syncthreads();
    float sum = 0.0f;
#pragma unroll
    for (int i = 0; i < 16; ++i) { p[i] = expf(p[i] - mx); sum += p[i]; }
    for (int off = 32; off; off >>= 1) sum += __shfl_down(sum, off);
    if ((t & 63) == 0) red[t >> 6] = sum;
    __syncthreads();
    float inv = 1.0f / (red[0] + red[1] + red[2] + red[3]);
    if (t == 0) { rowm[h * CM_ + row] = mx; rowinv[h * CM_ + row] = inv; }
    __syncthreads();
#pragma unroll
    for (int i = 0; i < 16; ++i) am[i] += 0.125f * p[i] * inv;
  }
  float* ar = attn + (size_t)row * N_ + t * 16;
#pragma unroll
  for (int i = 0; i < 16; ++i) ar[i] = am[i];
}

// gated combine (gate fused) + LN3
__global__ __launch_bounds__(128) void combine_ln3(const float* __restrict__ x,
    const float* __restrict__ xm, const float* __restrict__ xa,
    const float* __restrict__ gw, const float* __restrict__ gb,
    const float* __restrict__ g3, const float* __restrict__ b3,
    float* __restrict__ xc, u16* __restrict__ xn3b)
{
  int row = blockIdx.x, t = threadIdx.x;
  size_t base = (size_t)row * D_ + t * 4;
  f32x4 xv = *(const f32x4*)(x + base);
  f32x4 mv = *(const f32x4*)(xm + base);
  f32x4 av = *(const f32x4*)(xa + base);
  __shared__ float red[4];
  float gs = 0.0f;
#pragma unroll
  for (int i = 0; i < 4; ++i) { int c = t * 4 + i; gs += mv[i] * gw[c] + av[i] * gw[D_ + c]; }
  for (int off = 32; off; off >>= 1) gs += __shfl_down(gs, off);
  if ((t & 63) == 0) red[t >> 6] = gs;
  __syncthreads();
  float g = 1.0f / (1.0f + expf(-(red[0] + red[1] + gb[0])));
  __syncthreads();
  f32x4 cv = xv + g * mv + (1.0f - g) * av;
  *(f32x4*)(xc + base) = cv;
  float s = cv[0] + cv[1] + cv[2] + cv[3];
  float ss = cv[0]*cv[0] + cv[1]*cv[1] + cv[2]*cv[2] + cv[3]*cv[3];
  for (int off = 32; off; off >>= 1) { s += __shfl_down(s, off); ss += __shfl_down(ss, off); }
  if ((t & 63) == 0) { red[t >> 6] = s; red[2 + (t >> 6)] = ss; }
  __syncthreads();
  s = red[0] + red[1]; ss = red[2] + red[3];
  float mu = s * (1.0f / D_);
  float inv = rsqrtf(ss * (1.0f / D_) - mu * mu + 1e-5f);
#pragma unroll
  for (int i = 0; i < 4; ++i) {
    int c = t * 4 + i;
    float xh = (cv[i] - mu) * inv;
    xn3b[base + i] = f2bf(xh * g3[c] + b3[c]);
  }
}

// ------------------------------ launch ------------------------------

extern "C" void kernel_launch(void* const* d_in, const int* in_sizes, int n_in,
                              void* d_out, int out_size, void* d_ws, size_t ws_size,
                              hipStream_t stream)
{
  (void)in_sizes; (void)n_in; (void)out_size;
  const float* x         = (const float*)d_in[0];
  const int*   ei        = (const int*)d_in[1];
  const float* ln1_g     = (const float*)d_in[2];
  const float* ln1_b     = (const float*)d_in[3];
  const float* ln2_g     = (const float*)d_in[4];
  const float* ln2_b     = (const float*)d_in[5];
  const float* ln3_g     = (const float*)d_in[6];
  const float* ln3_b     = (const float*)d_in[7];
  const float* in_proj_w = (const float*)d_in[8];
  const float* in_proj_b = (const float*)d_in[9];
  const float* out_proj_w= (const float*)d_in[10];
  const float* out_proj_b= (const float*)d_in[11];
  const float* msg_w     = (const float*)d_in[12];
  const float* msg_b     = (const float*)d_in[13];
  const float* gru_wih   = (const float*)d_in[14];
  const float* gru_whh   = (const float*)d_in[15];
  const float* gru_bih   = (const float*)d_in[16];
  const float* gru_bhh   = (const float*)d_in[17];
  const float* ffn_w1    = (const float*)d_in[18];
  const float* ffn_b1    = (const float*)d_in[19];
  const float* ffn_w2    = (const float*)d_in[20];
  const float* ffn_b2    = (const float*)d_in[21];
  const float* gate_w    = (const float*)d_in[22];
  const float* gate_b    = (const float*)d_in[23];

  char* ws = (char*)d_ws;
  size_t o = 0;
  auto alloc = [&](size_t b) { size_t r = o; o += (b + 255) & ~(size_t)255; return r; };
  const size_t o_xn1   = alloc((size_t)N_ * D_ * 4);
  const size_t o_xn1b  = alloc((size_t)N_ * D_ * 2);
  const size_t o_xn2b  = alloc((size_t)N_ * D_ * 2);
  const size_t o_ipb   = alloc((size_t)TD_ * D_ * 2);
  const size_t o_w1b   = alloc((size_t)D_ * D_ * 2);
  const size_t o_wihb  = alloc((size_t)TD_ * D_ * 2);
  const size_t o_whhb  = alloc((size_t)TD_ * D_ * 2);  // whhb and w2b MUST be adjacent:
  const size_t o_w2b   = alloc((size_t)D_ * D_ * 2);   // catB = [whh(1536) | W2(512)] rows
  const size_t o_opb   = alloc((size_t)D_ * D_ * 2);
  const size_t o_f1b   = alloc((size_t)FD_ * D_ * 2);
  const size_t o_f2b   = alloc((size_t)D_ * FD_ * 2);
  const size_t o_bcat  = alloc((size_t)2048 * 4);
  const size_t o_degi  = alloc((size_t)N_ * 4);
  const size_t o_rs    = alloc((size_t)(N_ + 1) * 4);
  const size_t o_cur   = alloc((size_t)N_ * 4);
  const size_t o_ss    = alloc((size_t)E_ * 4);
  const size_t o_rowm  = alloc((size_t)H_ * CM_ * 4);
  const size_t o_rowi  = alloc((size_t)H_ * CM_ * 4);
  const size_t o_aggp  = alloc((size_t)N_ * D_ * 4);
  const size_t o_aggrb = alloc((size_t)N_ * D_ * 2);
  const size_t o_gsb   = alloc((size_t)N_ * D_ * 2);
  const size_t o_xm    = alloc((size_t)N_ * D_ * 4);
  const size_t o_xn3b  = alloc((size_t)N_ * D_ * 2);
  const size_t o_big1  = alloc((size_t)H_ * CM_ * N_ * 2);  // scc (per-chunk all-head scores)
  const size_t o_big2  = alloc((size_t)N_ * FD_ * 2);       // h1b
  const size_t o_rn    = alloc((size_t)N_ * TD_ * 4);       // gi -> qkvb+vT+ctx
  const size_t o_ro    = alloc((size_t)N_ * 2048 * 4);      // ghp -> xattn+xc
  if (ws_size < o) return;

  float* xn1  = (float*)(ws + o_xn1);
  u16* xn1b   = (u16*)(ws + o_xn1b);
  u16* xn2b   = (u16*)(ws + o_xn2b);
  u16* ipb    = (u16*)(ws + o_ipb);
  u16* w1b    = (u16*)(ws + o_w1b);
  u16* wihb   = (u16*)(ws + o_wihb);
  u16* whhb   = (u16*)(ws + o_whhb);
  u16* w2b    = (u16*)(ws + o_w2b);
  u16* opb    = (u16*)(ws + o_opb);
  u16* f1b    = (u16*)(ws + o_f1b);
  u16* f2b    = (u16*)(ws + o_f2b);
  float* bcat = (float*)(ws + o_bcat);
  int* degi   = (int*)(ws + o_degi);
  int* rs     = (int*)(ws + o_rs);
  int* cur    = (int*)(ws + o_cur);
  int* ssrc   = (int*)(ws + o_ss);
  float* rowm = (float*)(ws + o_rowm);
  float* rowi = (float*)(ws + o_rowi);
  float* aggp = (float*)(ws + o_aggp);
  u16* aggrb  = (u16*)(ws + o_aggrb);
  u16* gsb    = (u16*)(ws + o_gsb);
  float* xm   = (float*)(ws + o_xm);
  u16* xn3b   = (u16*)(ws + o_xn3b);
  u16* scc    = (u16*)(ws + o_big1);
  u16* h1b    = (u16*)(ws + o_big2);
  float* gi   = (float*)(ws + o_rn);
  u16* qkvb   = (u16*)(ws + o_rn);
  u16* vT     = (u16*)(ws + o_rn + (size_t)N_ * TD_ * 2);
  float* ctx  = (float*)(ws + o_rn + (size_t)N_ * TD_ * 2 + (size_t)D_ * N_ * 2);
  float* ghp  = (float*)(ws + o_ro);
  float* xattn= (float*)(ws + o_ro);
  float* xc   = (float*)(ws + o_ro + (size_t)N_ * D_ * 4);

  float* outp = (float*)d_out;
  float* attn = (float*)d_out + (size_t)N_ * D_;

  hipMemsetAsync(degi, 0, (size_t)N_ * 4, stream);

  // all weight conversions + biascat in one dispatch
  conv_weights<<<5122, 256, 0, stream>>>(in_proj_w, gru_wih, gru_whh, out_proj_w,
                                         ffn_w1, ffn_w2, msg_w, gru_bhh,
                                         ipb, wihb, whhb, opb, f1b, f2b, w1b, w2b, bcat);

  // LN1/LN2 (shared mean/var)
  ln12_kernel<<<N_, 128, 0, stream>>>(x, ln1_g, ln1_b, ln2_g, ln2_b, xn1, xn1b, xn2b);

  // CSR build: histogram -> scan -> scatter; then sparse gather-sum (f32 exact)
  hist_kernel<<<512, 256, 0, stream>>>(ei, degi);
  scan_kernel<<<1, 1024, 0, stream>>>(degi, rs, cur);
  scatter_kernel<<<512, 256, 0, stream>>>(ei, cur, ssrc);
  gather_kernel<<<N_, 128, 0, stream>>>(rs, ssrc, xn1, gsb);

  // ghp = xn1 @ [whh | W2]^T + [bhh | 0]   (gh cols 0..1535, part2 cols 1536..2047)
  gemm_bt<128, 128, 64, 2, 2, 4, 4, 0, true, 0, 0><<<dim3(32, 16), 256, 0, stream>>>(
      xn1b, D_, whhb, D_, ghp, 2048, bcat, 1.0f, D_, 0, 0, 0, nullptr, nullptr);
  // aggr_pre = gather_sum @ W1^T
  gemm_bt<64, 64, 64, 2, 2, 2, 2, 0, false, 0, 0><<<dim3(64, 8), 256, 0, stream>>>(
      gsb, D_, w1b, D_, aggp, D_, nullptr, 1.0f, D_, 0, 0, 0, nullptr, nullptr);
  finalize_aggr<<<8192, 256, 0, stream>>>(aggp, ghp, degi, msg_b, aggrb);

  // GRU input gates + update
  gemm_bt<128, 128, 64, 2, 2, 4, 4, 0, true, 0, 0><<<dim3(32, 12), 256, 0, stream>>>(
      aggrb, D_, wihb, D_, gi, TD_, gru_bih, 1.0f, D_, 0, 0, 0, nullptr, nullptr);
  gru_kernel<<<8192, 256, 0, stream>>>(gi, ghp, xn1, xm);

  // attention: qkv projection (gi region now dead)
  gemm_bt<128, 128, 64, 2, 2, 4, 4, 1, true, 0, 0><<<dim3(32, 12), 256, 0, stream>>>(
      xn2b, D_, ipb, D_, qkvb, TD_, in_proj_b, 1.0f, D_, 0, 0, 0, nullptr, nullptr);
  transpose_bf16<<<dim3(16, 128), dim3(32, 32), 0, stream>>>(qkvb + 1024, TD_, vT, N_);
  hipMemsetAsync(ctx, 0, (size_t)N_ * D_ * 4, stream);

  // chunked all-heads attention: scores -> softmax stats (+mean) -> PV (P recomputed)
  for (int c = 0; c < N_ / CM_; ++c) {
    gemm_bt<128, 128, 64, 2, 2, 4, 4, 1, false, 1, 0><<<dim3(CM_ / 128, 32, 8), 256, 0, stream>>>(
        qkvb + (size_t)c * CM_ * TD_, TD_, qkvb + 512, TD_, scc, N_, nullptr,
        0.125f, 64, 64, 64, (size_t)CM_ * N_, nullptr, nullptr);
    softmax_mh<<<CM_, 256, 0, stream>>>(scc, attn + (size_t)c * CM_ * N_, rowm, rowi);
    gemm_bt<64, 64, 64, 2, 2, 2, 2, 2, false, 2, 1><<<dim3(CM_ / 64, 8, 4), 256, 0, stream>>>(
        scc, N_, vT, N_, ctx + (size_t)c * CM_ * D_, D_, nullptr, 1.0f, 1024,
        (size_t)CM_ * N_, (size_t)64 * N_, 64, rowm, rowi);
  }

  // out_proj reads ctx (f32) directly via cast-staging
  gemm_bt<64, 64, 64, 2, 2, 2, 2, 0, true, 0, 2><<<dim3(64, 8), 256, 0, stream>>>(
      (const u16*)ctx, D_, opb, D_, xattn, D_, out_proj_b, 1.0f, D_, 0, 0, 0, nullptr, nullptr);

  // gated combine (gate fused) + LN3
  combine_ln3<<<N_, 128, 0, stream>>>(x, xm, xattn, gate_w, gate_b, ln3_g, ln3_b, xc, xn3b);

  // FFN: GELU fused in FFN1; residual add fused in FFN2 epilogue
  gemm_bt<128, 128, 64, 2, 2, 4, 4, 3, true, 0, 0><<<dim3(32, 16), 256, 0, stream>>>(
      xn3b, D_, f1b, D_, h1b, FD_, ffn_b1, 1.0f, D_, 0, 0, 0, nullptr, nullptr);
  gemm_bt<64, 64, 64, 2, 2, 2, 2, 4, true, 0, 0><<<dim3(64, 8), 256, 0, stream>>>(
      h1b, FD_, f2b, FD_, outp, D_, ffn_b2, 1.0f, FD_, 0, 0, 0, xc, nullptr);
}

// Round 6
// 572.705 us; speedup vs baseline: 2.1465x; 1.1444x over previous
//
#include <hip/hip_runtime.h>
#include <stdint.h>

#define N_ 4096
#define D_ 512
#define H_ 8
#define E_ 131072
#define TD_ 1536
#define FD_ 2048
#define CM_ 2048  // attention row-chunk (2 chunks)

typedef unsigned short u16;
typedef __bf16 bf16x8 __attribute__((ext_vector_type(8)));
typedef u16 u16x8 __attribute__((ext_vector_type(8)));
typedef u16 u16x4 __attribute__((ext_vector_type(4)));
typedef float f32x4 __attribute__((ext_vector_type(4)));

__device__ __forceinline__ u16 f2bf(float f) {
  union { float f; uint32_t u; } v; v.f = f;
  return (u16)((v.u + 0x7FFFu + ((v.u >> 16) & 1u)) >> 16);
}
__device__ __forceinline__ float bf2f(u16 b) {
  union { uint32_t u; float f; } v; v.u = ((uint32_t)b) << 16; return v.f;
}

__device__ __forceinline__ void gload16(const u16* g, u16* l) {
  __builtin_amdgcn_global_load_lds(
      (const __attribute__((address_space(1))) void*)(uintptr_t)g,
      (__attribute__((address_space(3))) void*)(uint32_t)(uintptr_t)l, 16, 0, 0);
}

// ---------------- GEMM: C[M,N] = A[M,K] @ B[N,K]^T (+bias) -----------------
// MODE: 0 f32 store, 1 bf16 store, 2 f32 atomicAdd, 3 exact-GELU bf16,
//       4 f32 store of (v + rowm[row*ldc+col])  (residual),
//       5 bf16 store of exp(v) + per-row sum atomicAdd into rowm[h*CM_+row],
//       6 f32 atomicAdd of v / rowm[h*CM_+row]  (PV with softmax denom),
//       7 bf16 store of (v + deg*(ghp_part2 + msg_b)) / max(deg,1)  (aggr)
// HM: 0 none (y=N-block, z=split-K); 1 z=head (A/B/C shifted); 2 y=head, z=split-K
// AMODE: 0 A bf16 via global_load_lds (source-swizzled); 2 A f32 cast->bf16 (reg-staged)
template <int BM, int BN, int BK, int WM, int WN, int FM, int FN, int MODE, bool BIAS,
          int HM, int AMODE>
__global__ __launch_bounds__(WM * WN * 64) void gemm_bt(
    const u16* __restrict__ A, int lda, const u16* __restrict__ B, int ldb,
    void* __restrict__ Cout, int ldc, const float* __restrict__ bias,
    float scale, int Kchunk, size_t hA, size_t hB, size_t hC,
    float* __restrict__ rowm, const float* __restrict__ rowinv,
    const int* __restrict__ auxI)
{
  static_assert(BM == WM * FM * 16 && BN == WN * FN * 16, "tile shape");
  static_assert(BK == 64, "LDS swizzle assumes BK=64");
  __shared__ alignas(16) u16 As[BM * BK];
  __shared__ alignas(16) u16 Bs[BN * BK];
  __shared__ float rsum[2][BM];   // only used by MODE 5
  constexpr int NT = WM * WN * 64;
  const int tid = threadIdx.x;
  const int lane = tid & 63;
  const int wave = tid >> 6;
  const long tm = (long)blockIdx.x * BM;
  long tn, k0;
  size_t cOff = 0;
  int hIdx = 0;
  if constexpr (HM == 1) {
    hIdx = blockIdx.z;
    A += (size_t)blockIdx.z * hA; B += (size_t)blockIdx.z * hB; cOff = (size_t)blockIdx.z * hC;
    tn = (long)blockIdx.y * BN; k0 = 0;
  } else if constexpr (HM == 2) {
    hIdx = blockIdx.y;
    A += (size_t)blockIdx.y * hA; B += (size_t)blockIdx.y * hB; cOff = (size_t)blockIdx.y * hC;
    tn = 0; k0 = (long)blockIdx.z * Kchunk;
  } else {
    tn = (long)blockIdx.y * BN; k0 = (long)blockIdx.z * Kchunk;
  }
  const int wm0 = (wave / WN) * (FM * 16);
  const int wn0 = (wave % WN) * (FN * 16);

  f32x4 acc[FM][FN] = {};

  constexpr int A_LOADS = (BM * BK) / (NT * 8);
  constexpr int B_LOADS = (BN * BK) / (NT * 8);

  for (int kt = 0; kt < Kchunk; kt += BK) {
    const long kb = k0 + kt;
#pragma unroll
    for (int i = 0; i < A_LOADS; ++i) {
      if constexpr (AMODE == 0) {
        int sB = (i * NT + wave * 64) * 8;
        int s = sB + lane * 8;
        int row = s / BK;
        int blk = (s % BK) >> 3;
        gload16(A + (tm + row) * (long)lda + kb + ((blk ^ (row & 7)) << 3), As + sB);
      } else {
        int s = (i * NT + tid) * 8;
        int row = s / BK, kk = s % BK;
        const float* Af = (const float*)A;
        f32x4 lo = *(const f32x4*)(Af + (tm + row) * (long)lda + kb + kk);
        f32x4 hi = *(const f32x4*)(Af + (tm + row) * (long)lda + kb + kk + 4);
        u16x8 w;
#pragma unroll
        for (int k = 0; k < 4; ++k) { w[k] = f2bf(lo[k]); w[4 + k] = f2bf(hi[k]); }
        *(u16x8*)(&As[row * BK + (kk ^ ((row & 7) << 3))]) = w;
      }
    }
#pragma unroll
    for (int i = 0; i < B_LOADS; ++i) {
      int sB = (i * NT + wave * 64) * 8;
      int s = sB + lane * 8;
      int row = s / BK;
      int blk = (s % BK) >> 3;
      gload16(B + (tn + row) * (long)ldb + kb + ((blk ^ (row & 7)) << 3), Bs + sB);
    }
    __syncthreads();
#pragma unroll
    for (int kk = 0; kk < BK; kk += 32) {
      bf16x8 af[FM], bfr[FN];
#pragma unroll
      for (int i = 0; i < FM; ++i) {
        int ar = wm0 + i * 16 + (lane & 15);
        int ac = kk + (lane >> 4) * 8;
        af[i] = *(const bf16x8*)(&As[ar * BK + (ac ^ ((ar & 7) << 3))]);
      }
#pragma unroll
      for (int j = 0; j < FN; ++j) {
        int br = wn0 + j * 16 + (lane & 15);
        int bc = kk + (lane >> 4) * 8;
        bfr[j] = *(const bf16x8*)(&Bs[br * BK + (bc ^ ((br & 7) << 3))]);
      }
#pragma unroll
      for (int i = 0; i < FM; ++i)
#pragma unroll
        for (int j = 0; j < FN; ++j)
          acc[i][j] = __builtin_amdgcn_mfma_f32_16x16x32_bf16(af[i], bfr[j], acc[i][j], 0, 0, 0);
    }
    __syncthreads();
  }

  if constexpr (MODE == 5) {
    // exp + per-row sum: write P' = exp(acc*scale), reduce rows into rowm
#pragma unroll
    for (int i = 0; i < FM; ++i) {
      float part[4] = {0.0f, 0.0f, 0.0f, 0.0f};
#pragma unroll
      for (int j = 0; j < FN; ++j) {
        const long col = tn + wn0 + j * 16 + (lane & 15);
#pragma unroll
        for (int r = 0; r < 4; ++r) {
          const long row = tm + wm0 + i * 16 + (lane >> 4) * 4 + r;
          float p = expf(acc[i][j][r] * scale);
          ((u16*)Cout)[cOff + row * (long)ldc + col] = f2bf(p);
          part[r] += p;
        }
      }
#pragma unroll
      for (int r = 0; r < 4; ++r) {
        float s = part[r];
        s += __shfl_xor(s, 1); s += __shfl_xor(s, 2);
        s += __shfl_xor(s, 4); s += __shfl_xor(s, 8);
        if ((lane & 15) == 0)
          rsum[wave & 1][wm0 + i * 16 + (lane >> 4) * 4 + r] = s;
      }
    }
    __syncthreads();
    for (int t = tid; t < BM; t += NT)
      atomicAdd(&rowm[(size_t)hIdx * CM_ + tm + t], rsum[0][t] + rsum[1][t]);
    return;
  }

#pragma unroll
  for (int i = 0; i < FM; ++i) {
#pragma unroll
    for (int j = 0; j < FN; ++j) {
      const long col = tn + wn0 + j * 16 + (lane & 15);
      float bv = 0.0f;
      if constexpr (BIAS) {
        if (MODE != 2 || blockIdx.z == 0) bv = bias[col];
      }
#pragma unroll
      for (int r = 0; r < 4; ++r) {
        const long row = tm + wm0 + i * 16 + (lane >> 4) * 4 + r;
        float v = acc[i][j][r] * scale + bv;
        if constexpr (MODE == 0) {
          ((float*)Cout)[cOff + row * (long)ldc + col] = v;
        } else if constexpr (MODE == 1) {
          ((u16*)Cout)[cOff + row * (long)ldc + col] = f2bf(v);
        } else if constexpr (MODE == 2) {
          atomicAdd(&((float*)Cout)[cOff + row * (long)ldc + col], v);
        } else if constexpr (MODE == 3) {
          float ge = 0.5f * v * (1.0f + erff(v * 0.70710678118654752f));
          ((u16*)Cout)[cOff + row * (long)ldc + col] = f2bf(ge);
        } else if constexpr (MODE == 4) {
          ((float*)Cout)[cOff + row * (long)ldc + col] = v + rowm[row * (long)ldc + col];
        } else if constexpr (MODE == 6) {
          float inv = 1.0f / rowm[(size_t)hIdx * CM_ + row];
          atomicAdd(&((float*)Cout)[cOff + row * (long)ldc + col], v * inv);
        } else {  // MODE 7: aggr finalize
          float dg = (float)auxI[row];
          float p2 = rowm[(size_t)row * 2048 + 1536 + col];
          float vv = (v + dg * (p2 + rowinv[col])) / fmaxf(dg, 1.0f);
          ((u16*)Cout)[cOff + row * (long)ldc + col] = f2bf(vv);
        }
      }
    }
  }
}

// ---------------- elementwise / CSR / reduction kernels ----------------

__global__ void conv_weights(const float* __restrict__ ip, const float* __restrict__ wih,
    const float* __restrict__ whh, const float* __restrict__ op,
    const float* __restrict__ f1, const float* __restrict__ f2, const float* __restrict__ mw,
    const float* __restrict__ gbhh,
    u16* __restrict__ ipb, u16* __restrict__ wihb, u16* __restrict__ whhb,
    u16* __restrict__ opb, u16* __restrict__ f1b, u16* __restrict__ f2b,
    u16* __restrict__ w1b, u16* __restrict__ w2b, float* __restrict__ biascat)
{
  int i = (blockIdx.x * 256 + threadIdx.x) * 4;
  if (i >= 5244928) return;
  if (i >= 5242880) {           // biascat[2048] = [gru_bhh | 0]
    int j = i - 5242880;
#pragma unroll
    for (int k = 0; k < 4; ++k) biascat[j + k] = (j + k < TD_) ? gbhh[j + k] : 0.0f;
    return;
  }
  if (i >= 4718592) {           // msg_w [512][1024] -> w1b | w2b
    int j = i - 4718592;
    int r = j >> 10, c = j & 1023;
    f32x4 v = *(const f32x4*)(mw + j);
    u16* d = (c < 512 ? w1b + r * 512 + c : w2b + r * 512 + (c - 512));
#pragma unroll
    for (int k = 0; k < 4; ++k) d[k] = f2bf(v[k]);
    return;
  }
  const float* src; u16* dst; int off;
  if      (i < 786432)  { src = ip;  dst = ipb;  off = i; }
  else if (i < 1572864) { src = wih; dst = wihb; off = i - 786432; }
  else if (i < 2359296) { src = whh; dst = whhb; off = i - 1572864; }
  else if (i < 2621440) { src = op;  dst = opb;  off = i - 2359296; }
  else if (i < 3670016) { src = f1;  dst = f1b;  off = i - 2621440; }
  else                  { src = f2;  dst = f2b;  off = i - 3670016; }
  f32x4 v = *(const f32x4*)(src + off);
#pragma unroll
  for (int k = 0; k < 4; ++k) dst[off + k] = f2bf(v[k]);
}

__global__ __launch_bounds__(1024) void transpose_bf16(const u16* __restrict__ src, int sld,
                                                       u16* __restrict__ dst, int dld) {
  __shared__ u16 tile[32][33];
  int r = blockIdx.y * 32 + threadIdx.y;
  int c = blockIdx.x * 32 + threadIdx.x;
  tile[threadIdx.y][threadIdx.x] = src[(size_t)r * sld + c];
  __syncthreads();
  int rr = blockIdx.x * 32 + threadIdx.y;
  int cc = blockIdx.y * 32 + threadIdx.x;
  dst[(size_t)rr * dld + cc] = tile[threadIdx.x][threadIdx.y];
}

__global__ void hist_kernel(const int* __restrict__ ei, int* __restrict__ degi) {
  int e = blockIdx.x * 256 + threadIdx.x;
  atomicAdd(&degi[ei[E_ + e]], 1);
}

__global__ __launch_bounds__(1024) void scan_kernel(const int* __restrict__ degi,
    int* __restrict__ rowstart, int* __restrict__ cursor) {
  __shared__ int sums[1024];
  int t = threadIdx.x;
  int b = t * 4;
  int d0 = degi[b], d1 = degi[b + 1], d2 = degi[b + 2], d3 = degi[b + 3];
  int tot = d0 + d1 + d2 + d3;
  sums[t] = tot;
  __syncthreads();
  for (int off = 1; off < 1024; off <<= 1) {
    int v = (t >= off) ? sums[t - off] : 0;
    __syncthreads();
    sums[t] += v;
    __syncthreads();
  }
  int excl = (t > 0) ? sums[t - 1] : 0;
  rowstart[b] = excl; rowstart[b + 1] = excl + d0;
  rowstart[b + 2] = excl + d0 + d1; rowstart[b + 3] = excl + d0 + d1 + d2;
  cursor[b] = excl; cursor[b + 1] = excl + d0;
  cursor[b + 2] = excl + d0 + d1; cursor[b + 3] = excl + d0 + d1 + d2;
  if (t == 1023) rowstart[N_] = excl + tot;
}

__global__ void scatter_kernel(const int* __restrict__ ei, int* __restrict__ cursor,
                               int* __restrict__ ss) {
  int e = blockIdx.x * 256 + threadIdx.x;
  int d = ei[E_ + e];
  int pos = atomicAdd(&cursor[d], 1);
  ss[pos] = ei[e];
}

// per-dst gather-sum of xn1 rows (bf16 in, f32 accum), bf16 out
__global__ __launch_bounds__(128) void gather_kernel(const int* __restrict__ rs,
    const int* __restrict__ ss, const u16* __restrict__ xn1b, u16* __restrict__ gsb) {
  int dst = blockIdx.x, t = threadIdx.x;
  int s0 = rs[dst], s1 = rs[dst + 1];
  __shared__ int sl[128];
  float a0 = 0, a1 = 0, a2 = 0, a3 = 0;
  for (int base = s0; base < s1; base += 128) {
    int n = min(128, s1 - base);
    if (t < n) sl[t] = ss[base + t];
    __syncthreads();
    for (int j = 0; j < n; ++j) {
      u16x4 v = *(const u16x4*)(xn1b + (size_t)sl[j] * D_ + t * 4);
      a0 += bf2f(v[0]); a1 += bf2f(v[1]); a2 += bf2f(v[2]); a3 += bf2f(v[3]);
    }
    __syncthreads();
  }
  u16* dp = gsb + (size_t)dst * D_ + t * 4;
  dp[0] = f2bf(a0); dp[1] = f2bf(a1); dp[2] = f2bf(a2); dp[3] = f2bf(a3);
}

__global__ __launch_bounds__(128) void ln12_kernel(const float* __restrict__ x,
    const float* __restrict__ g1, const float* __restrict__ b1,
    const float* __restrict__ g2, const float* __restrict__ b2,
    u16* __restrict__ xn1b, u16* __restrict__ xn2b)
{
  int row = blockIdx.x, t = threadIdx.x;
  size_t base = (size_t)row * D_ + t * 4;
  f32x4 v = *(const f32x4*)(x + base);
  float s = v[0] + v[1] + v[2] + v[3];
  float ss = v[0]*v[0] + v[1]*v[1] + v[2]*v[2] + v[3]*v[3];
  __shared__ float red[4];
  for (int off = 32; off; off >>= 1) { s += __shfl_down(s, off); ss += __shfl_down(ss, off); }
  if ((t & 63) == 0) { red[t >> 6] = s; red[2 + (t >> 6)] = ss; }
  __syncthreads();
  s = red[0] + red[1]; ss = red[2] + red[3];
  float mu = s * (1.0f / D_);
  float inv = rsqrtf(ss * (1.0f / D_) - mu * mu + 1e-5f);
#pragma unroll
  for (int i = 0; i < 4; ++i) {
    int c = t * 4 + i;
    float xh = (v[i] - mu) * inv;
    xn1b[base + i] = f2bf(xh * g1[c] + b1[c]);
    xn2b[base + i] = f2bf(xh * g2[c] + b2[c]);
  }
}

__global__ void gru_kernel(const float* __restrict__ gi, const float* __restrict__ ghp,
                           const u16* __restrict__ xn1b, float* __restrict__ xm) {
  int i = blockIdx.x * 256 + threadIdx.x;
  int n = i >> 9, d = i & 511;
  size_t bi = (size_t)n * TD_ + d;
  size_t bh = (size_t)n * 2048 + d;
  float ir = gi[bi], iz = gi[bi + 512], in_ = gi[bi + 1024];
  float hr = ghp[bh], hz = ghp[bh + 512], hn = ghp[bh + 1024];
  float r = 1.0f / (1.0f + expf(-(ir + hr)));
  float z = 1.0f / (1.0f + expf(-(iz + hz)));
  float nn = tanhf(in_ + r * hn);
  xm[i] = (1.0f - z) * nn + z * bf2f(xn1b[i]);
}

// attn[q,:] = (1/8) sum_h P'_h[q,:] / rowsum_h[q]   — pure streaming
__global__ __launch_bounds__(256) void mean_kernel(const u16* __restrict__ sc,
    const float* __restrict__ rowsum, float* __restrict__ attn) {
  const int row = blockIdx.x, t = threadIdx.x;
  float am[16] = {};
  for (int h = 0; h < H_; ++h) {
    const u16* wr = sc + (size_t)h * ((size_t)CM_ * N_) + (size_t)row * N_ + t * 16;
    float inv = 0.125f / rowsum[(size_t)h * CM_ + row];
    u16x8 v0 = *(const u16x8*)(wr);
    u16x8 v1 = *(const u16x8*)(wr + 8);
#pragma unroll
    for (int i = 0; i < 8; ++i) { am[i] += bf2f(v0[i]) * inv; am[8 + i] += bf2f(v1[i]) * inv; }
  }
  float* ar = attn + (size_t)row * N_ + t * 16;
#pragma unroll
  for (int i = 0; i < 16; ++i) ar[i] = am[i];
}

// gated combine (gate fused) + LN3
__global__ __launch_bounds__(128) void combine_ln3(const float* __restrict__ x,
    const float* __restrict__ xm, const float* __restrict__ xa,
    const float* __restrict__ gw, const float* __restrict__ gb,
    const float* __restrict__ g3, const float* __restrict__ b3,
    float* __restrict__ xc, u16* __restrict__ xn3b)
{
  int row = blockIdx.x, t = threadIdx.x;
  size_t base = (size_t)row * D_ + t * 4;
  f32x4 xv = *(const f32x4*)(x + base);
  f32x4 mv = *(const f32x4*)(xm + base);
  f32x4 av = *(const f32x4*)(xa + base);
  __shared__ float red[4];
  float gs = 0.0f;
#pragma unroll
  for (int i = 0; i < 4; ++i) { int c = t * 4 + i; gs += mv[i] * gw[c] + av[i] * gw[D_ + c]; }
  for (int off = 32; off; off >>= 1) gs += __shfl_down(gs, off);
  if ((t & 63) == 0) red[t >> 6] = gs;
  __syncthreads();
  float g = 1.0f / (1.0f + expf(-(red[0] + red[1] + gb[0])));
  __syncthreads();
  f32x4 cv = xv + g * mv + (1.0f - g) * av;
  *(f32x4*)(xc + base) = cv;
  float s = cv[0] + cv[1] + cv[2] + cv[3];
  float ss = cv[0]*cv[0] + cv[1]*cv[1] + cv[2]*cv[2] + cv[3]*cv[3];
  for (int off = 32; off; off >>= 1) { s += __shfl_down(s, off); ss += __shfl_down(ss, off); }
  if ((t & 63) == 0) { red[t >> 6] = s; red[2 + (t >> 6)] = ss; }
  __syncthreads();
  s = red[0] + red[1]; ss = red[2] + red[3];
  float mu = s * (1.0f / D_);
  float inv = rsqrtf(ss * (1.0f / D_) - mu * mu + 1e-5f);
#pragma unroll
  for (int i = 0; i < 4; ++i) {
    int c = t * 4 + i;
    float xh = (cv[i] - mu) * inv;
    xn3b[base + i] = f2bf(xh * g3[c] + b3[c]);
  }
}

// ------------------------------ launch ------------------------------

extern "C" void kernel_launch(void* const* d_in, const int* in_sizes, int n_in,
                              void* d_out, int out_size, void* d_ws, size_t ws_size,
                              hipStream_t stream)
{
  (void)in_sizes; (void)n_in; (void)out_size;
  const float* x         = (const float*)d_in[0];
  const int*   ei        = (const int*)d_in[1];
  const float* ln1_g     = (const float*)d_in[2];
  const float* ln1_b     = (const float*)d_in[3];
  const float* ln2_g     = (const float*)d_in[4];
  const float* ln2_b     = (const float*)d_in[5];
  const float* ln3_g     = (const float*)d_in[6];
  const float* ln3_b     = (const float*)d_in[7];
  const float* in_proj_w = (const float*)d_in[8];
  const float* in_proj_b = (const float*)d_in[9];
  const float* out_proj_w= (const float*)d_in[10];
  const float* out_proj_b= (const float*)d_in[11];
  const float* msg_w     = (const float*)d_in[12];
  const float* msg_b     = (const float*)d_in[13];
  const float* gru_wih   = (const float*)d_in[14];
  const float* gru_whh   = (const float*)d_in[15];
  const float* gru_bih   = (const float*)d_in[16];
  const float* gru_bhh   = (const float*)d_in[17];
  const float* ffn_w1    = (const float*)d_in[18];
  const float* ffn_b1    = (const float*)d_in[19];
  const float* ffn_w2    = (const float*)d_in[20];
  const float* ffn_b2    = (const float*)d_in[21];
  const float* gate_w    = (const float*)d_in[22];
  const float* gate_b    = (const float*)d_in[23];

  char* ws = (char*)d_ws;
  size_t o = 0;
  auto alloc = [&](size_t b) { size_t r = o; o += (b + 255) & ~(size_t)255; return r; };
  const size_t o_xn1b  = alloc((size_t)N_ * D_ * 2);
  const size_t o_xn2b  = alloc((size_t)N_ * D_ * 2);
  const size_t o_ipb   = alloc((size_t)TD_ * D_ * 2);
  const size_t o_w1b   = alloc((size_t)D_ * D_ * 2);
  const size_t o_wihb  = alloc((size_t)TD_ * D_ * 2);
  const size_t o_whhb  = alloc((size_t)TD_ * D_ * 2);  // whhb & w2b adjacent: [whh|W2]
  const size_t o_w2b   = alloc((size_t)D_ * D_ * 2);
  const size_t o_opb   = alloc((size_t)D_ * D_ * 2);
  const size_t o_f1b   = alloc((size_t)FD_ * D_ * 2);
  const size_t o_f2b   = alloc((size_t)D_ * FD_ * 2);
  const size_t o_bcat  = alloc((size_t)2048 * 4);
  const size_t o_degi  = alloc((size_t)N_ * 4);
  const size_t o_rs    = alloc((size_t)(N_ + 1) * 4);
  const size_t o_cur   = alloc((size_t)N_ * 4);
  const size_t o_ss    = alloc((size_t)E_ * 4);
  const size_t o_rsum  = alloc((size_t)H_ * N_ * 4);   // per-chunk slabs of H_*CM_
  const size_t o_aggrb = alloc((size_t)N_ * D_ * 2);
  const size_t o_gsb   = alloc((size_t)N_ * D_ * 2);
  const size_t o_xm    = alloc((size_t)N_ * D_ * 4);
  const size_t o_xn3b  = alloc((size_t)N_ * D_ * 2);
  const size_t o_big1  = alloc((size_t)H_ * CM_ * N_ * 2);  // scc P' (134 MB)
  const size_t o_big2  = alloc((size_t)N_ * FD_ * 2);       // h1b
  const size_t o_rn    = alloc((size_t)N_ * TD_ * 4);       // gi -> qkvb+vT+ctx
  const size_t o_ro    = alloc((size_t)N_ * 2048 * 4);      // ghp -> xattn+xc
  if (ws_size < o) return;

  u16* xn1b   = (u16*)(ws + o_xn1b);
  u16* xn2b   = (u16*)(ws + o_xn2b);
  u16* ipb    = (u16*)(ws + o_ipb);
  u16* w1b    = (u16*)(ws + o_w1b);
  u16* wihb   = (u16*)(ws + o_wihb);
  u16* whhb   = (u16*)(ws + o_whhb);
  u16* w2b    = (u16*)(ws + o_w2b);
  u16* opb    = (u16*)(ws + o_opb);
  u16* f1b    = (u16*)(ws + o_f1b);
  u16* f2b    = (u16*)(ws + o_f2b);
  float* bcat = (float*)(ws + o_bcat);
  int* degi   = (int*)(ws + o_degi);
  int* rs     = (int*)(ws + o_rs);
  int* cur    = (int*)(ws + o_cur);
  int* ssrc   = (int*)(ws + o_ss);
  float* rsumA= (float*)(ws + o_rsum);
  u16* aggrb  = (u16*)(ws + o_aggrb);
  u16* gsb    = (u16*)(ws + o_gsb);
  float* xm   = (float*)(ws + o_xm);
  u16* xn3b   = (u16*)(ws + o_xn3b);
  u16* scc    = (u16*)(ws + o_big1);
  u16* h1b    = (u16*)(ws + o_big2);
  float* gi   = (float*)(ws + o_rn);
  u16* qkvb   = (u16*)(ws + o_rn);
  u16* vT     = (u16*)(ws + o_rn + (size_t)N_ * TD_ * 2);
  float* ctx  = (float*)(ws + o_rn + (size_t)N_ * TD_ * 2 + (size_t)D_ * N_ * 2);
  float* ghp  = (float*)(ws + o_ro);
  float* xattn= (float*)(ws + o_ro);
  float* xc   = (float*)(ws + o_ro + (size_t)N_ * D_ * 4);

  float* outp = (float*)d_out;
  float* attn = (float*)d_out + (size_t)N_ * D_;

  hipMemsetAsync(degi, 0, (size_t)N_ * 4, stream);
  hipMemsetAsync(rsumA, 0, (size_t)H_ * N_ * 4, stream);

  conv_weights<<<5122, 256, 0, stream>>>(in_proj_w, gru_wih, gru_whh, out_proj_w,
                                         ffn_w1, ffn_w2, msg_w, gru_bhh,
                                         ipb, wihb, whhb, opb, f1b, f2b, w1b, w2b, bcat);

  ln12_kernel<<<N_, 128, 0, stream>>>(x, ln1_g, ln1_b, ln2_g, ln2_b, xn1b, xn2b);

  // CSR build + sparse gather-sum
  hist_kernel<<<512, 256, 0, stream>>>(ei, degi);
  scan_kernel<<<1, 1024, 0, stream>>>(degi, rs, cur);
  scatter_kernel<<<512, 256, 0, stream>>>(ei, cur, ssrc);
  gather_kernel<<<N_, 128, 0, stream>>>(rs, ssrc, xn1b, gsb);

  // ghp = xn1 @ [whh | W2]^T + [bhh | 0]
  gemm_bt<128, 128, 64, 2, 2, 4, 4, 0, true, 0, 0><<<dim3(32, 16), 256, 0, stream>>>(
      xn1b, D_, whhb, D_, ghp, 2048, bcat, 1.0f, D_, 0, 0, 0, nullptr, nullptr, nullptr);
  // aggr = finalize(gather_sum @ W1^T)  (MODE 7, fused)
  gemm_bt<64, 64, 64, 2, 2, 2, 2, 7, false, 0, 0><<<dim3(64, 8), 256, 0, stream>>>(
      gsb, D_, w1b, D_, aggrb, D_, nullptr, 1.0f, D_, 0, 0, 0, ghp, msg_b, degi);

  // GRU input gates + update
  gemm_bt<128, 128, 64, 2, 2, 4, 4, 0, true, 0, 0><<<dim3(32, 12), 256, 0, stream>>>(
      aggrb, D_, wihb, D_, gi, TD_, gru_bih, 1.0f, D_, 0, 0, 0, nullptr, nullptr, nullptr);
  gru_kernel<<<8192, 256, 0, stream>>>(gi, ghp, xn1b, xm);

  // qkv projection (gi region now dead)
  gemm_bt<128, 128, 64, 2, 2, 4, 4, 1, true, 0, 0><<<dim3(32, 12), 256, 0, stream>>>(
      xn2b, D_, ipb, D_, qkvb, TD_, in_proj_b, 1.0f, D_, 0, 0, 0, nullptr, nullptr, nullptr);
  transpose_bf16<<<dim3(16, 128), dim3(32, 32), 0, stream>>>(qkvb + 1024, TD_, vT, N_);
  hipMemsetAsync(ctx, 0, (size_t)N_ * D_ * 4, stream);

  // attention: scores+exp+rowsum -> streaming mean -> DMA PV (2 chunks of 2048)
  for (int c = 0; c < N_ / CM_; ++c) {
    float* rsumC = rsumA + (size_t)c * H_ * CM_;
    gemm_bt<128, 128, 64, 2, 2, 4, 4, 5, false, 1, 0><<<dim3(CM_ / 128, 32, 8), 256, 0, stream>>>(
        qkvb + (size_t)c * CM_ * TD_, TD_, qkvb + 512, TD_, scc, N_, nullptr,
        0.125f, 64, 64, 64, (size_t)CM_ * N_, rsumC, nullptr, nullptr);
    mean_kernel<<<CM_, 256, 0, stream>>>(scc, rsumC, attn + (size_t)c * CM_ * N_);
    gemm_bt<64, 64, 64, 2, 2, 2, 2, 6, false, 2, 0><<<dim3(CM_ / 64, 8, 8), 256, 0, stream>>>(
        scc, N_, vT, N_, ctx + (size_t)c * CM_ * D_, D_, nullptr, 1.0f, 512,
        (size_t)CM_ * N_, (size_t)64 * N_, 64, rsumC, nullptr, nullptr);
  }

  // out_proj (ctx f32 cast-staged)
  gemm_bt<64, 64, 64, 2, 2, 2, 2, 0, true, 0, 2><<<dim3(64, 8), 256, 0, stream>>>(
      (const u16*)ctx, D_, opb, D_, xattn, D_, out_proj_b, 1.0f, D_, 0, 0, 0,
      nullptr, nullptr, nullptr);

  combine_ln3<<<N_, 128, 0, stream>>>(x, xm, xattn, gate_w, gate_b, ln3_g, ln3_b, xc, xn3b);

  // FFN: GELU fused; residual fused in FFN2 epilogue
  gemm_bt<128, 128, 64, 2, 2, 4, 4, 3, true, 0, 0><<<dim3(32, 16), 256, 0, stream>>>(
      xn3b, D_, f1b, D_, h1b, FD_, ffn_b1, 1.0f, D_, 0, 0, 0, nullptr, nullptr, nullptr);
  gemm_bt<64, 64, 64, 2, 2, 2, 2, 4, true, 0, 0><<<dim3(64, 8), 256, 0, stream>>>(
      h1b, FD_, f2b, FD_, outp, D_, ffn_b2, 1.0f, FD_, 0, 0, 0, xc, nullptr, nullptr);
}